// Round 1
// baseline (475.881 us; speedup 1.0000x reference)
//
#include <hip/hip_runtime.h>

typedef unsigned short u16;
typedef unsigned int u32;
typedef unsigned long long u64;
typedef __attribute__((ext_vector_type(8))) short short8;
typedef __attribute__((ext_vector_type(4))) float f32x4;

#define BSHIFT 8               // 256 rows per bucket
#define MAXBUCK 512

__device__ __forceinline__ float bf2f(u32 u) {
    union { u32 i; float f; } v; v.i = u << 16; return v.f;
}
__device__ __forceinline__ u16 f2bf(float f) {
    union { float f; u32 i; } v; v.f = f;
    u32 u = (v.i + 0x7fffu + ((v.i >> 16) & 1u)) >> 16;
    return (u16)u;
}

// ---------------- fused: cast x -> bf16 row-major  +  pack weights (with -Wh copy) ----------------
// W pack layout per layer: 4 matrices [Wl, -Wh, Wh, Wm], each MFMA-B-fragment packed:
// u16 idx = (T*4 + c)*512 + lane*8 + j ; col = T*16 + (lane&15), k = c*32 + (lane>>4)*8 + j.
#define CASTBLK 2048
__global__ void k_prep(const float4* __restrict__ X, u32* __restrict__ Xb, long total4,
                       const float* __restrict__ Wl1, const float* __restrict__ Wh1,
                       const float* __restrict__ Wm1, const float* __restrict__ Wl2,
                       const float* __restrict__ Wh2, const float* __restrict__ Wm2,
                       u16* __restrict__ Wp1, u16* __restrict__ Wp2) {
    if (blockIdx.x < CASTBLK) {
        long i = (long)blockIdx.x * blockDim.x + threadIdx.x;
        long stride = (long)CASTBLK * blockDim.x;
        for (; i < total4; i += stride) {
            float4 p = X[i];
            Xb[i * 2 + 0] = (u32)f2bf(p.x) | ((u32)f2bf(p.y) << 16);
            Xb[i * 2 + 1] = (u32)f2bf(p.z) | ((u32)f2bf(p.w) << 16);
        }
        return;
    }
    int tid = (blockIdx.x - CASTBLK) * blockDim.x + threadIdx.x;
    int nthr = 16 * blockDim.x;
    for (int m = 0; m < 8; ++m) {
        int layer = m >> 2;          // 0: L1, 1: L2
        int slot = m & 3;            // 0 Wl, 1 -Wh, 2 Wh, 3 Wm
        int Hout = layer ? 64 : 128;
        const float* W = layer ? (slot == 0 ? Wl2 : (slot == 3 ? Wm2 : Wh2))
                               : (slot == 0 ? Wl1 : (slot == 3 ? Wm1 : Wh1));
        float sgn = (slot == 1) ? -1.f : 1.f;
        u16* dst = (layer ? Wp2 : Wp1) + slot * Hout * 128;
        int total = 128 * Hout;
        for (int i = tid; i < total; i += nthr) {
            int T = i / 2048;
            int c = (i / 512) & 3;
            int lane = (i / 8) & 63;
            int j = i & 7;
            int col = T * 16 + (lane & 15);
            int k = c * 32 + (lane >> 4) * 8 + j;
            dst[i] = f2bf(sgn * W[k * Hout + col]);
        }
    }
}

// ---------------- CSR build: degree + row_ptr scan ----------------
__global__ void k_deg(const int* __restrict__ erow, int e, int* __restrict__ deg) {
    int i = blockIdx.x * blockDim.x + threadIdx.x;
    if (i < e) atomicAdd(&deg[erow[i]], 1);
}

__global__ void k_scan_a(const int* __restrict__ deg, int n, int* __restrict__ bsum) {
    __shared__ int lds[256];
    int b = blockIdx.x, t = threadIdx.x;
    int base = b * 1024;
    int s = 0;
    for (int i = t; i < 1024; i += 256) { int idx = base + i; if (idx < n) s += deg[idx]; }
    lds[t] = s; __syncthreads();
    for (int off = 128; off > 0; off >>= 1) { if (t < off) lds[t] += lds[t + off]; __syncthreads(); }
    if (t == 0) bsum[b] = lds[0];
}

__global__ void k_scan_b(const int* __restrict__ bsum, int nb, int* __restrict__ boff) {
    __shared__ int lds[256];
    int t = threadIdx.x;
    int v = (t < nb) ? bsum[t] : 0;
    lds[t] = v; __syncthreads();
    for (int off = 1; off < 256; off <<= 1) {
        int x = (t >= off) ? lds[t - off] : 0;
        __syncthreads();
        lds[t] += x;
        __syncthreads();
    }
    if (t < nb) boff[t] = lds[t] - v;
}

// also initializes gcursor at bucket boundaries (row % 256 == 0)
__global__ void k_scan_c(const int* __restrict__ deg, int n, const int* __restrict__ boff,
                         int* __restrict__ row_ptr, float* __restrict__ inv_deg,
                         int* __restrict__ gcursor) {
    __shared__ int lds[256];
    int b = blockIdx.x, t = threadIdx.x;
    int base = b * 1024 + t * 4;
    int v0 = 0, v1 = 0, v2 = 0, v3 = 0;
    if (base + 0 < n) v0 = deg[base + 0];
    if (base + 1 < n) v1 = deg[base + 1];
    if (base + 2 < n) v2 = deg[base + 2];
    if (base + 3 < n) v3 = deg[base + 3];
    int s = v0 + v1 + v2 + v3;
    lds[t] = s; __syncthreads();
    for (int off = 1; off < 256; off <<= 1) {
        int x = (t >= off) ? lds[t - off] : 0;
        __syncthreads();
        lds[t] += x;
        __syncthreads();
    }
    int run = boff[b] + lds[t] - s;
    if (base + 0 < n) { row_ptr[base + 0] = run; if (((base + 0) & 255) == 0) gcursor[(base + 0) >> BSHIFT] = run; inv_deg[base + 0] = v0 > 0 ? 1.f / v0 : 0.f; run += v0; }
    if (base + 1 < n) { row_ptr[base + 1] = run; inv_deg[base + 1] = v1 > 0 ? 1.f / v1 : 0.f; run += v1; }
    if (base + 2 < n) { row_ptr[base + 2] = run; inv_deg[base + 2] = v2 > 0 ? 1.f / v2 : 0.f; run += v2; }
    if (base + 3 < n) { row_ptr[base + 3] = run; inv_deg[base + 3] = v3 > 0 ? 1.f / v3 : 0.f; run += v3; }
    if (b == gridDim.x - 1 && t == 255) row_ptr[n] = run;
}

// ---------------- bucketed edge sort; bedge packed u32 = (col<<8) | (row & 255) ----------------
__global__ void k_bscatter(const int* __restrict__ erow, const int* __restrict__ ecol, int e,
                           int nbuck, int* __restrict__ gcursor, u32* __restrict__ bedge) {
    __shared__ int hist[MAXBUCK];
    __shared__ int base[MAXBUCK];
    for (int t = threadIdx.x; t < nbuck; t += blockDim.x) hist[t] = 0;
    __syncthreads();
    int chunk = (e + gridDim.x - 1) / gridDim.x;
    int lo = blockIdx.x * chunk, hi = min(e, lo + chunk);
    for (int i = lo + threadIdx.x; i < hi; i += blockDim.x)
        atomicAdd(&hist[erow[i] >> BSHIFT], 1);
    __syncthreads();
    for (int t = threadIdx.x; t < nbuck; t += blockDim.x) {
        int c = hist[t];
        base[t] = c ? atomicAdd(&gcursor[t], c) : 0;
        hist[t] = 0;
    }
    __syncthreads();
    for (int i = lo + threadIdx.x; i < hi; i += blockDim.x) {
        int r = erow[i];
        int bk = r >> BSHIFT;
        int pos = base[bk] + atomicAdd(&hist[bk], 1);
        bedge[pos] = ((u32)ecol[i] << 8) | (u32)(r & 255);
    }
}

__global__ void k_bfill(const u32* __restrict__ bedge, const int* __restrict__ row_ptr, int n,
                        int* __restrict__ cols) {
    __shared__ int cur[1 << BSHIFT];
    int b = blockIdx.x;
    for (int t = threadIdx.x; t < (1 << BSHIFT); t += blockDim.x) cur[t] = 0;
    __syncthreads();
    int rbase = b << BSHIFT;
    int rend = min(n, rbase + (1 << BSHIFT));
    int lo = row_ptr[rbase], hi = row_ptr[rend];
    for (int i = lo + threadIdx.x; i < hi; i += blockDim.x) {
        u32 v = bedge[i];
        int rl = (int)(v & 255u);
        int c = (int)(v >> 8);
        int p = row_ptr[rbase + rl] + atomicAdd(&cur[rl], 1);
        cols[p] = c;
    }
}

// ---------------- SpMM: bf16 X row-major in; A-fragment-packed S (=adj@X scaled) and X out ----------------
// R10: 2 rows per wave (32-lane halves), u64 gathers: one VMEM instr moves 512B across 2 rows
// (2x bytes-in-flight/wave, 0.5x shfl+address VALU per byte, 0.5x wave count).
// Degree divergence between halves handled by exec mask (beg/end uniform per half).
__global__ void k_spmm(const u32* __restrict__ X2, const int* __restrict__ row_ptr,
                       const int* __restrict__ cols, const float* __restrict__ inv_deg,
                       u32* __restrict__ Sp, u32* __restrict__ Xp, int n) {
    int wave = (int)((blockIdx.x * blockDim.x + threadIdx.x) >> 6);
    int lane = threadIdx.x & 63;
    int sl = lane & 31;                 // lane within half
    int row = wave * 2 + (lane >> 5);   // half 0 -> even row, half 1 -> odd row
    if (row >= n) return;
    const u64* X4 = (const u64*)X2;     // lane sl covers u32 cols {2sl, 2sl+1} = 4 bf16
    int beg = row_ptr[row], end = row_ptr[row + 1];
    u64 px = X4[(size_t)row * 32 + sl]; // self row, issued early to overlap gather loop
    float a0 = 0.f, a1 = 0.f, a2 = 0.f, a3 = 0.f;
    for (int j0 = beg; j0 < end; j0 += 32) {
        int cnt = end - j0; if (cnt > 32) cnt = 32;
        int myc = (sl < cnt) ? cols[j0 + sl] : 0;
        int j = 0;
        for (; j + 8 <= cnt; j += 8) {
            int c0 = __shfl(myc, j + 0, 32);
            int c1 = __shfl(myc, j + 1, 32);
            int c2 = __shfl(myc, j + 2, 32);
            int c3 = __shfl(myc, j + 3, 32);
            int c4 = __shfl(myc, j + 4, 32);
            int c5 = __shfl(myc, j + 5, 32);
            int c6 = __shfl(myc, j + 6, 32);
            int c7 = __shfl(myc, j + 7, 32);
            u64 p0 = X4[(size_t)c0 * 32 + sl];
            u64 p1 = X4[(size_t)c1 * 32 + sl];
            u64 p2 = X4[(size_t)c2 * 32 + sl];
            u64 p3 = X4[(size_t)c3 * 32 + sl];
            u64 p4 = X4[(size_t)c4 * 32 + sl];
            u64 p5 = X4[(size_t)c5 * 32 + sl];
            u64 p6 = X4[(size_t)c6 * 32 + sl];
            u64 p7 = X4[(size_t)c7 * 32 + sl];
            u32 l0 = (u32)p0, h0 = (u32)(p0 >> 32);
            u32 l1 = (u32)p1, h1 = (u32)(p1 >> 32);
            u32 l2 = (u32)p2, h2 = (u32)(p2 >> 32);
            u32 l3 = (u32)p3, h3 = (u32)(p3 >> 32);
            u32 l4 = (u32)p4, h4 = (u32)(p4 >> 32);
            u32 l5 = (u32)p5, h5 = (u32)(p5 >> 32);
            u32 l6 = (u32)p6, h6 = (u32)(p6 >> 32);
            u32 l7 = (u32)p7, h7 = (u32)(p7 >> 32);
            a0 += bf2f(l0 & 0xffffu) + bf2f(l1 & 0xffffu) + bf2f(l2 & 0xffffu) + bf2f(l3 & 0xffffu)
                + bf2f(l4 & 0xffffu) + bf2f(l5 & 0xffffu) + bf2f(l6 & 0xffffu) + bf2f(l7 & 0xffffu);
            a1 += bf2f(l0 >> 16) + bf2f(l1 >> 16) + bf2f(l2 >> 16) + bf2f(l3 >> 16)
                + bf2f(l4 >> 16) + bf2f(l5 >> 16) + bf2f(l6 >> 16) + bf2f(l7 >> 16);
            a2 += bf2f(h0 & 0xffffu) + bf2f(h1 & 0xffffu) + bf2f(h2 & 0xffffu) + bf2f(h3 & 0xffffu)
                + bf2f(h4 & 0xffffu) + bf2f(h5 & 0xffffu) + bf2f(h6 & 0xffffu) + bf2f(h7 & 0xffffu);
            a3 += bf2f(h0 >> 16) + bf2f(h1 >> 16) + bf2f(h2 >> 16) + bf2f(h3 >> 16)
                + bf2f(h4 >> 16) + bf2f(h5 >> 16) + bf2f(h6 >> 16) + bf2f(h7 >> 16);
        }
        for (; j + 4 <= cnt; j += 4) {
            int c0 = __shfl(myc, j + 0, 32);
            int c1 = __shfl(myc, j + 1, 32);
            int c2 = __shfl(myc, j + 2, 32);
            int c3 = __shfl(myc, j + 3, 32);
            u64 p0 = X4[(size_t)c0 * 32 + sl];
            u64 p1 = X4[(size_t)c1 * 32 + sl];
            u64 p2 = X4[(size_t)c2 * 32 + sl];
            u64 p3 = X4[(size_t)c3 * 32 + sl];
            u32 l0 = (u32)p0, h0 = (u32)(p0 >> 32);
            u32 l1 = (u32)p1, h1 = (u32)(p1 >> 32);
            u32 l2 = (u32)p2, h2 = (u32)(p2 >> 32);
            u32 l3 = (u32)p3, h3 = (u32)(p3 >> 32);
            a0 += bf2f(l0 & 0xffffu) + bf2f(l1 & 0xffffu) + bf2f(l2 & 0xffffu) + bf2f(l3 & 0xffffu);
            a1 += bf2f(l0 >> 16) + bf2f(l1 >> 16) + bf2f(l2 >> 16) + bf2f(l3 >> 16);
            a2 += bf2f(h0 & 0xffffu) + bf2f(h1 & 0xffffu) + bf2f(h2 & 0xffffu) + bf2f(h3 & 0xffffu);
            a3 += bf2f(h0 >> 16) + bf2f(h1 >> 16) + bf2f(h2 >> 16) + bf2f(h3 >> 16);
        }
        for (; j < cnt; ++j) {
            int c = __shfl(myc, j, 32);
            u64 p = X4[(size_t)c * 32 + sl];
            u32 lo = (u32)p, hi = (u32)(p >> 32);
            a0 += bf2f(lo & 0xffffu);
            a1 += bf2f(lo >> 16);
            a2 += bf2f(hi & 0xffffu);
            a3 += bf2f(hi >> 16);
        }
    }
    float s = inv_deg[row];
    a0 *= s; a1 *= s; a2 *= s; a3 *= s;
    // fragment store: u32 col u0 = 2*sl (even), u1 = u0+1 are adjacent (same cc,qq; jj,jj+1)
    int u0 = sl * 2;
    int cc = u0 >> 4, qq = (u0 >> 2) & 3, jj = u0 & 3;   // jj in {0,2}
    size_t dst = (size_t)(row >> 4) * 1024 + cc * 256 + qq * 64 + (row & 15) * 4 + jj;
    u64 sv = (u64)((u32)f2bf(a0) | ((u32)f2bf(a1) << 16))
           | ((u64)((u32)f2bf(a2) | ((u32)f2bf(a3) << 16)) << 32);
    *(u64*)(Sp + dst) = sv;   // 8B aligned: dst = 4k + {0,2}
    *(u64*)(Xp + dst) = px;
}

// ---------------- fused GEMM + attention combine; A = {S, X}; W = [Wl, -Wh, Wh, Wm] ----------------
// out_low = S@Wl, out_high = S@(-Wh) + X@Wh, out_mlp = X@Wm.
// MT=4 (64 rows/block): ~84 VGPR -> 6 waves/SIMD; grid (n/64) ~ 1563 blocks -> 6 blocks/CU.  [R8: MT=8 gave 7.8% occupancy, 75 us]
template<int HOUT, int MT, bool L1>
__global__ __launch_bounds__(256)
void k_gemm_comb(const u16* __restrict__ Sp, const u16* __restrict__ Xp,
                 const u16* __restrict__ Wp,
                 const float* __restrict__ vl, const float* __restrict__ vh, const float* __restrict__ vm,
                 const float* __restrict__ att, int n,
                 u16* __restrict__ feaOut, float* __restrict__ fOut) {
    constexpr int KPG = HOUT / 64;
    constexpr int NTw = 3 * KPG;
    constexpr int ROWS = MT * 16;
    int w = threadIdx.x >> 6, lane = threadIdx.x & 63;
    int ln15 = lane & 15, lq = lane >> 4;
    int m0 = blockIdx.x * ROWS;

    f32x4 acc[MT][NTw];
#pragma unroll
    for (int mt = 0; mt < MT; ++mt)
#pragma unroll
        for (int k = 0; k < NTw; ++k) { f32x4 z = {0.f, 0.f, 0.f, 0.f}; acc[mt][k] = z; }

    for (int c = 0; c < 4; ++c) {
        short8 bl[KPG], bhn[KPG], bhp[KPG], bm[KPG];
#pragma unroll
        for (int kk = 0; kk < KPG; ++kk) {
            int Tl = w + kk * 4;
            size_t fo = (size_t)(Tl * 4 + c) * 512 + lane * 8;
            bl[kk]  = *(const short8*)(Wp + (size_t)0 * (HOUT * 128) + fo);
            bhn[kk] = *(const short8*)(Wp + (size_t)1 * (HOUT * 128) + fo);
            bhp[kk] = *(const short8*)(Wp + (size_t)2 * (HOUT * 128) + fo);
            bm[kk]  = *(const short8*)(Wp + (size_t)3 * (HOUT * 128) + fo);
        }
#pragma unroll
        for (int mt = 0; mt < MT; ++mt) {
            size_t off = ((size_t)((m0 >> 4) + mt) * 4 + c) * 512 + lane * 8;
            short8 as = *(const short8*)(Sp + off);
            short8 ax = *(const short8*)(Xp + off);
#pragma unroll
            for (int kk = 0; kk < KPG; ++kk) {
                acc[mt][0 * KPG + kk] = __builtin_amdgcn_mfma_f32_16x16x32_bf16(as, bl[kk], acc[mt][0 * KPG + kk], 0, 0, 0);
                acc[mt][1 * KPG + kk] = __builtin_amdgcn_mfma_f32_16x16x32_bf16(as, bhn[kk], acc[mt][1 * KPG + kk], 0, 0, 0);
                acc[mt][1 * KPG + kk] = __builtin_amdgcn_mfma_f32_16x16x32_bf16(ax, bhp[kk], acc[mt][1 * KPG + kk], 0, 0, 0);
                acc[mt][2 * KPG + kk] = __builtin_amdgcn_mfma_f32_16x16x32_bf16(ax, bm[kk], acc[mt][2 * KPG + kk], 0, 0, 0);
            }
        }
    }

    float vval[NTw];
#pragma unroll
    for (int k = 0; k < NTw; ++k) {
        int g = k / KPG, kk = k % KPG;
        int col = w * 16 + kk * 64 + ln15;
        vval[k] = (g == 0 ? vl : (g == 1 ? vh : vm))[col];
    }

    __shared__ float part[4][3][ROWS];
    __shared__ float wgt[ROWS][3];
#pragma unroll
    for (int mt = 0; mt < MT; ++mt) {
        float pdg[3][4];
#pragma unroll
        for (int g = 0; g < 3; ++g)
#pragma unroll
            for (int r = 0; r < 4; ++r) pdg[g][r] = 0.f;
#pragma unroll
        for (int k = 0; k < NTw; ++k) {
            int g = k / KPG;
#pragma unroll
            for (int r = 0; r < 4; ++r)
                pdg[g][r] += fmaxf(acc[mt][k][r], 0.f) * vval[k];
        }
#pragma unroll
        for (int off = 1; off < 16; off <<= 1)
#pragma unroll
            for (int g = 0; g < 3; ++g)
#pragma unroll
                for (int r = 0; r < 4; ++r)
                    pdg[g][r] += __shfl_xor(pdg[g][r], off);
        if (ln15 == 0) {
#pragma unroll
            for (int g = 0; g < 3; ++g)
#pragma unroll
                for (int r = 0; r < 4; ++r)
                    part[w][g][mt * 16 + lq * 4 + r] = pdg[g][r];
        }
    }
    __syncthreads();
    if (threadIdx.x < ROWS) {
        int row = threadIdx.x;
        float d0 = part[0][0][row] + part[1][0][row] + part[2][0][row] + part[3][0][row];
        float d1 = part[0][1][row] + part[1][1][row] + part[2][1][row] + part[3][1][row];
        float d2 = part[0][2][row] + part[1][2][row] + part[2][2][row] + part[3][2][row];
        float s0 = 1.f / (1.f + __expf(-d0));
        float s1 = 1.f / (1.f + __expf(-d1));
        float s2 = 1.f / (1.f + __expf(-d2));
        float a0 = (s0 * att[0] + s1 * att[3] + s2 * att[6]) * (1.f / 3.f);
        float a1 = (s0 * att[1] + s1 * att[4] + s2 * att[7]) * (1.f / 3.f);
        float a2 = (s0 * att[2] + s1 * att[5] + s2 * att[8]) * (1.f / 3.f);
        float mx = fmaxf(a0, fmaxf(a1, a2));
        float e0 = __expf(a0 - mx), e1 = __expf(a1 - mx), e2 = __expf(a2 - mx);
        float inv = 3.f / (e0 + e1 + e2);
        wgt[row][0] = e0 * inv;
        wgt[row][1] = e1 * inv;
        wgt[row][2] = e2 * inv;
    }
    __syncthreads();

#pragma unroll
    for (int mt = 0; mt < MT; ++mt)
#pragma unroll
        for (int kk = 0; kk < KPG; ++kk)
#pragma unroll
            for (int r = 0; r < 4; ++r) {
                int row_local = mt * 16 + lq * 4 + r;
                int row = m0 + row_local;
                if (row < n) {
                    int col = w * 16 + kk * 64 + ln15;
                    float w0 = wgt[row_local][0], w1 = wgt[row_local][1], w2 = wgt[row_local][2];
                    float ol = fmaxf(acc[mt][0 * KPG + kk][r], 0.f);
                    float oh = fmaxf(acc[mt][1 * KPG + kk][r], 0.f);
                    float om = fmaxf(acc[mt][2 * KPG + kk][r], 0.f);
                    float val = w0 * ol + w1 * oh + w2 * om;
                    if (L1)
                        feaOut[(size_t)row * HOUT + col] = f2bf(fmaxf(val, 0.f));
                    else
                        fOut[(size_t)row * HOUT + col] = val;
                }
            }
}

extern "C" void kernel_launch(void* const* d_in, const int* in_sizes, int n_in,
                              void* d_out, int out_size, void* d_ws, size_t ws_size,
                              hipStream_t stream) {
    const int F = 128;
    int n = in_sizes[0] / F;
    int e = in_sizes[1] / 2;
    int n64 = (n + 63) & ~63;
    int nbuck = (n + (1 << BSHIFT) - 1) >> BSHIFT;
    const float* x = (const float*)d_in[0];
    const int* ei = (const int*)d_in[1];
    const int* erow = ei;
    const int* ecol = ei + e;
    const float *Wl1 = (const float*)d_in[2], *Wh1 = (const float*)d_in[3], *Wm1 = (const float*)d_in[4];
    const float *vl1 = (const float*)d_in[5], *vh1 = (const float*)d_in[6], *vm1 = (const float*)d_in[7];
    const float* att1 = (const float*)d_in[8];
    const float *Wl2 = (const float*)d_in[9], *Wh2 = (const float*)d_in[10], *Wm2 = (const float*)d_in[11];
    const float *vl2 = (const float*)d_in[12], *vh2 = (const float*)d_in[13], *vm2 = (const float*)d_in[14];
    const float* att2 = (const float*)d_in[15];
    float* out = (float*)d_out;

    char* ws = (char*)d_ws;
    size_t off = 0;
    auto alloc = [&](size_t b) -> void* {
        void* p = ws + off;
        off = (off + b + 255) & ~(size_t)255;
        return p;
    };
    int* deg = (int*)alloc((size_t)n * 4);
    int* row_ptr = (int*)alloc((size_t)(n + 1) * 4);
    float* inv_deg = (float*)alloc((size_t)n * 4);
    int* bsum = (int*)alloc(1024);
    int* boff = (int*)alloc(1024);
    int* gcursor = (int*)alloc(MAXBUCK * 4);
    u32* bedge = (u32*)alloc((size_t)e * 4);
    int* cols = (int*)alloc((size_t)e * 4);
    u32* Sp = (u32*)alloc((size_t)n64 * 64 * 4);
    u32* Xp = (u32*)alloc((size_t)n64 * 64 * 4);
    u32* Fp = (u32*)alloc((size_t)n64 * 64 * 4);
    u16* Xb = (u16*)alloc((size_t)n * 128 * 2);
    u16* fea = (u16*)alloc((size_t)n * 128 * 2);
    u16* Wp1 = (u16*)alloc((size_t)4 * 128 * 128 * 2);
    u16* Wp2 = (u16*)alloc((size_t)4 * 64 * 128 * 2);
    (void)ws_size; (void)n_in; (void)out_size;

    const int tb = 256;
    k_prep<<<CASTBLK + 16, 256, 0, stream>>>((const float4*)x, (u32*)Xb, (long)n * 32,
                                             Wl1, Wh1, Wm1, Wl2, Wh2, Wm2, Wp1, Wp2);

    hipMemsetAsync(deg, 0, (size_t)n * 4, stream);
    k_deg<<<(e + tb - 1) / tb, tb, 0, stream>>>(erow, e, deg);
    int nb = (n + 1023) / 1024;
    k_scan_a<<<nb, 256, 0, stream>>>(deg, n, bsum);
    k_scan_b<<<1, 256, 0, stream>>>(bsum, nb, boff);
    k_scan_c<<<nb, 256, 0, stream>>>(deg, n, boff, row_ptr, inv_deg, gcursor);

    k_bscatter<<<256, 256, 0, stream>>>(erow, ecol, e, nbuck, gcursor, bedge);
    k_bfill<<<nbuck, 256, 0, stream>>>(bedge, row_ptr, n, cols);

    int wb = (n + 7) / 8;      // 4 waves/block x 2 rows/wave = 8 rows/block
    int gb = n64 / 64;

    // layer 1
    k_spmm<<<wb, 256, 0, stream>>>((const u32*)Xb, row_ptr, cols, inv_deg, Sp, Xp, n);
    k_gemm_comb<128, 4, true><<<gb, 256, 0, stream>>>((const u16*)Sp, (const u16*)Xp,
                                                      Wp1, vl1, vh1, vm1, att1, n, fea, nullptr);

    // layer 2
    k_spmm<<<wb, 256, 0, stream>>>((const u32*)fea, row_ptr, cols, inv_deg, Sp, Fp, n);
    k_gemm_comb<64, 4, false><<<gb, 256, 0, stream>>>((const u16*)Sp, (const u16*)Fp,
                                                      Wp2, vl2, vh2, vm2, att2, n, nullptr, out);
}

// Round 2
// 463.619 us; speedup vs baseline: 1.0264x; 1.0264x over previous
//
#include <hip/hip_runtime.h>

typedef unsigned short u16;
typedef unsigned int u32;
typedef unsigned long long u64;
typedef __attribute__((ext_vector_type(8))) short short8;
typedef __attribute__((ext_vector_type(4))) float f32x4;

#define BSHIFT 8               // 256 rows per bucket
#define MAXBUCK 512

__device__ __forceinline__ float bf2f(u32 u) {
    union { u32 i; float f; } v; v.i = u << 16; return v.f;
}
__device__ __forceinline__ u16 f2bf(float f) {
    union { float f; u32 i; } v; v.f = f;
    u32 u = (v.i + 0x7fffu + ((v.i >> 16) & 1u)) >> 16;
    return (u16)u;
}

// bijective XCD-chunked swizzle (m204 form): chunk c -> XCD c/q' so that contiguous
// row ranges live on one XCD in BOTH producer (spmm) and consumer (gemm) grids.
__device__ __forceinline__ int xcd_swz(int bid, int nbg) {
    int q = nbg >> 3, r = nbg & 7;
    int x = bid & 7, i = bid >> 3;
    return (x < r) ? (x * (q + 1) + i) : (r * (q + 1) + (x - r) * q + i);
}

// ---------------- fused: cast x -> bf16 row-major  +  pack weights (with -Wh copy) ----------------
// W pack layout per layer: 4 matrices [Wl, -Wh, Wh, Wm], each MFMA-B-fragment packed:
// u16 idx = (T*4 + c)*512 + lane*8 + j ; col = T*16 + (lane&15), k = c*32 + (lane>>4)*8 + j.
#define CASTBLK 2048
__global__ void k_prep(const float4* __restrict__ X, u32* __restrict__ Xb, long total4,
                       const float* __restrict__ Wl1, const float* __restrict__ Wh1,
                       const float* __restrict__ Wm1, const float* __restrict__ Wl2,
                       const float* __restrict__ Wh2, const float* __restrict__ Wm2,
                       u16* __restrict__ Wp1, u16* __restrict__ Wp2) {
    if (blockIdx.x < CASTBLK) {
        long i = (long)blockIdx.x * blockDim.x + threadIdx.x;
        long stride = (long)CASTBLK * blockDim.x;
        for (; i < total4; i += stride) {
            float4 p = X[i];
            Xb[i * 2 + 0] = (u32)f2bf(p.x) | ((u32)f2bf(p.y) << 16);
            Xb[i * 2 + 1] = (u32)f2bf(p.z) | ((u32)f2bf(p.w) << 16);
        }
        return;
    }
    int tid = (blockIdx.x - CASTBLK) * blockDim.x + threadIdx.x;
    int nthr = 16 * blockDim.x;
    for (int m = 0; m < 8; ++m) {
        int layer = m >> 2;          // 0: L1, 1: L2
        int slot = m & 3;            // 0 Wl, 1 -Wh, 2 Wh, 3 Wm
        int Hout = layer ? 64 : 128;
        const float* W = layer ? (slot == 0 ? Wl2 : (slot == 3 ? Wm2 : Wh2))
                               : (slot == 0 ? Wl1 : (slot == 3 ? Wm1 : Wh1));
        float sgn = (slot == 1) ? -1.f : 1.f;
        u16* dst = (layer ? Wp2 : Wp1) + slot * Hout * 128;
        int total = 128 * Hout;
        for (int i = tid; i < total; i += nthr) {
            int T = i / 2048;
            int c = (i / 512) & 3;
            int lane = (i / 8) & 63;
            int j = i & 7;
            int col = T * 16 + (lane & 15);
            int k = c * 32 + (lane >> 4) * 8 + j;
            dst[i] = f2bf(sgn * W[k * Hout + col]);
        }
    }
}

// ---------------- CSR build: degree + row_ptr scan ----------------
__global__ void k_deg(const int* __restrict__ erow, int e, int* __restrict__ deg) {
    int i = blockIdx.x * blockDim.x + threadIdx.x;
    if (i < e) atomicAdd(&deg[erow[i]], 1);
}

__global__ void k_scan_a(const int* __restrict__ deg, int n, int* __restrict__ bsum) {
    __shared__ int lds[256];
    int b = blockIdx.x, t = threadIdx.x;
    int base = b * 1024;
    int s = 0;
    for (int i = t; i < 1024; i += 256) { int idx = base + i; if (idx < n) s += deg[idx]; }
    lds[t] = s; __syncthreads();
    for (int off = 128; off > 0; off >>= 1) { if (t < off) lds[t] += lds[t + off]; __syncthreads(); }
    if (t == 0) bsum[b] = lds[0];
}

__global__ void k_scan_b(const int* __restrict__ bsum, int nb, int* __restrict__ boff) {
    __shared__ int lds[256];
    int t = threadIdx.x;
    int v = (t < nb) ? bsum[t] : 0;
    lds[t] = v; __syncthreads();
    for (int off = 1; off < 256; off <<= 1) {
        int x = (t >= off) ? lds[t - off] : 0;
        __syncthreads();
        lds[t] += x;
        __syncthreads();
    }
    if (t < nb) boff[t] = lds[t] - v;
}

// also initializes gcursor at bucket boundaries (row % 256 == 0)
__global__ void k_scan_c(const int* __restrict__ deg, int n, const int* __restrict__ boff,
                         int* __restrict__ row_ptr, float* __restrict__ inv_deg,
                         int* __restrict__ gcursor) {
    __shared__ int lds[256];
    int b = blockIdx.x, t = threadIdx.x;
    int base = b * 1024 + t * 4;
    int v0 = 0, v1 = 0, v2 = 0, v3 = 0;
    if (base + 0 < n) v0 = deg[base + 0];
    if (base + 1 < n) v1 = deg[base + 1];
    if (base + 2 < n) v2 = deg[base + 2];
    if (base + 3 < n) v3 = deg[base + 3];
    int s = v0 + v1 + v2 + v3;
    lds[t] = s; __syncthreads();
    for (int off = 1; off < 256; off <<= 1) {
        int x = (t >= off) ? lds[t - off] : 0;
        __syncthreads();
        lds[t] += x;
        __syncthreads();
    }
    int run = boff[b] + lds[t] - s;
    if (base + 0 < n) { row_ptr[base + 0] = run; if (((base + 0) & 255) == 0) gcursor[(base + 0) >> BSHIFT] = run; inv_deg[base + 0] = v0 > 0 ? 1.f / v0 : 0.f; run += v0; }
    if (base + 1 < n) { row_ptr[base + 1] = run; inv_deg[base + 1] = v1 > 0 ? 1.f / v1 : 0.f; run += v1; }
    if (base + 2 < n) { row_ptr[base + 2] = run; inv_deg[base + 2] = v2 > 0 ? 1.f / v2 : 0.f; run += v2; }
    if (base + 3 < n) { row_ptr[base + 3] = run; inv_deg[base + 3] = v3 > 0 ? 1.f / v3 : 0.f; run += v3; }
    if (b == gridDim.x - 1 && t == 255) row_ptr[n] = run;
}

// ---------------- bucketed edge sort; bedge packed u32 = (col<<8) | (row & 255) ----------------
__global__ void k_bscatter(const int* __restrict__ erow, const int* __restrict__ ecol, int e,
                           int nbuck, int* __restrict__ gcursor, u32* __restrict__ bedge) {
    __shared__ int hist[MAXBUCK];
    __shared__ int base[MAXBUCK];
    for (int t = threadIdx.x; t < nbuck; t += blockDim.x) hist[t] = 0;
    __syncthreads();
    int chunk = (e + gridDim.x - 1) / gridDim.x;
    int lo = blockIdx.x * chunk, hi = min(e, lo + chunk);
    for (int i = lo + threadIdx.x; i < hi; i += blockDim.x)
        atomicAdd(&hist[erow[i] >> BSHIFT], 1);
    __syncthreads();
    for (int t = threadIdx.x; t < nbuck; t += blockDim.x) {
        int c = hist[t];
        base[t] = c ? atomicAdd(&gcursor[t], c) : 0;
        hist[t] = 0;
    }
    __syncthreads();
    for (int i = lo + threadIdx.x; i < hi; i += blockDim.x) {
        int r = erow[i];
        int bk = r >> BSHIFT;
        int pos = base[bk] + atomicAdd(&hist[bk], 1);
        bedge[pos] = ((u32)ecol[i] << 8) | (u32)(r & 255);
    }
}

__global__ void k_bfill(const u32* __restrict__ bedge, const int* __restrict__ row_ptr, int n,
                        int* __restrict__ cols) {
    __shared__ int cur[1 << BSHIFT];
    int b = blockIdx.x;
    for (int t = threadIdx.x; t < (1 << BSHIFT); t += blockDim.x) cur[t] = 0;
    __syncthreads();
    int rbase = b << BSHIFT;
    int rend = min(n, rbase + (1 << BSHIFT));
    int lo = row_ptr[rbase], hi = row_ptr[rend];
    for (int i = lo + threadIdx.x; i < hi; i += blockDim.x) {
        u32 v = bedge[i];
        int rl = (int)(v & 255u);
        int c = (int)(v >> 8);
        int p = row_ptr[rbase + rl] + atomicAdd(&cur[rl], 1);
        cols[p] = c;
    }
}

// ---------------- SpMM: bf16 X row-major in; A-fragment-packed S (=adj@X scaled) and X out ----------------
// R10: 2 rows per wave (32-lane halves), u64 gathers. R11: XCD swizzle matched with gemm so the
// fragments a gemm block reads were written on the same XCD's L2.
__global__ void k_spmm(const u32* __restrict__ X2, const int* __restrict__ row_ptr,
                       const int* __restrict__ cols, const float* __restrict__ inv_deg,
                       u32* __restrict__ Sp, u32* __restrict__ Xp, int n) {
    int blk = xcd_swz(blockIdx.x, gridDim.x);
    int wave = blk * 4 + (int)(threadIdx.x >> 6);
    int lane = threadIdx.x & 63;
    int sl = lane & 31;                 // lane within half
    int row = wave * 2 + (lane >> 5);   // half 0 -> even row, half 1 -> odd row
    if (row >= n) return;
    const u64* X4 = (const u64*)X2;     // lane sl covers u32 cols {2sl, 2sl+1} = 4 bf16
    int beg = row_ptr[row], end = row_ptr[row + 1];
    u64 px = X4[(size_t)row * 32 + sl]; // self row, issued early to overlap gather loop
    float a0 = 0.f, a1 = 0.f, a2 = 0.f, a3 = 0.f;
    for (int j0 = beg; j0 < end; j0 += 32) {
        int cnt = end - j0; if (cnt > 32) cnt = 32;
        int myc = (sl < cnt) ? cols[j0 + sl] : 0;
        int j = 0;
        for (; j + 8 <= cnt; j += 8) {
            int c0 = __shfl(myc, j + 0, 32);
            int c1 = __shfl(myc, j + 1, 32);
            int c2 = __shfl(myc, j + 2, 32);
            int c3 = __shfl(myc, j + 3, 32);
            int c4 = __shfl(myc, j + 4, 32);
            int c5 = __shfl(myc, j + 5, 32);
            int c6 = __shfl(myc, j + 6, 32);
            int c7 = __shfl(myc, j + 7, 32);
            u64 p0 = X4[(size_t)c0 * 32 + sl];
            u64 p1 = X4[(size_t)c1 * 32 + sl];
            u64 p2 = X4[(size_t)c2 * 32 + sl];
            u64 p3 = X4[(size_t)c3 * 32 + sl];
            u64 p4 = X4[(size_t)c4 * 32 + sl];
            u64 p5 = X4[(size_t)c5 * 32 + sl];
            u64 p6 = X4[(size_t)c6 * 32 + sl];
            u64 p7 = X4[(size_t)c7 * 32 + sl];
            u32 l0 = (u32)p0, h0 = (u32)(p0 >> 32);
            u32 l1 = (u32)p1, h1 = (u32)(p1 >> 32);
            u32 l2 = (u32)p2, h2 = (u32)(p2 >> 32);
            u32 l3 = (u32)p3, h3 = (u32)(p3 >> 32);
            u32 l4 = (u32)p4, h4 = (u32)(p4 >> 32);
            u32 l5 = (u32)p5, h5 = (u32)(p5 >> 32);
            u32 l6 = (u32)p6, h6 = (u32)(p6 >> 32);
            u32 l7 = (u32)p7, h7 = (u32)(p7 >> 32);
            a0 += bf2f(l0 & 0xffffu) + bf2f(l1 & 0xffffu) + bf2f(l2 & 0xffffu) + bf2f(l3 & 0xffffu)
                + bf2f(l4 & 0xffffu) + bf2f(l5 & 0xffffu) + bf2f(l6 & 0xffffu) + bf2f(l7 & 0xffffu);
            a1 += bf2f(l0 >> 16) + bf2f(l1 >> 16) + bf2f(l2 >> 16) + bf2f(l3 >> 16)
                + bf2f(l4 >> 16) + bf2f(l5 >> 16) + bf2f(l6 >> 16) + bf2f(l7 >> 16);
            a2 += bf2f(h0 & 0xffffu) + bf2f(h1 & 0xffffu) + bf2f(h2 & 0xffffu) + bf2f(h3 & 0xffffu)
                + bf2f(h4 & 0xffffu) + bf2f(h5 & 0xffffu) + bf2f(h6 & 0xffffu) + bf2f(h7 & 0xffffu);
            a3 += bf2f(h0 >> 16) + bf2f(h1 >> 16) + bf2f(h2 >> 16) + bf2f(h3 >> 16)
                + bf2f(h4 >> 16) + bf2f(h5 >> 16) + bf2f(h6 >> 16) + bf2f(h7 >> 16);
        }
        for (; j + 4 <= cnt; j += 4) {
            int c0 = __shfl(myc, j + 0, 32);
            int c1 = __shfl(myc, j + 1, 32);
            int c2 = __shfl(myc, j + 2, 32);
            int c3 = __shfl(myc, j + 3, 32);
            u64 p0 = X4[(size_t)c0 * 32 + sl];
            u64 p1 = X4[(size_t)c1 * 32 + sl];
            u64 p2 = X4[(size_t)c2 * 32 + sl];
            u64 p3 = X4[(size_t)c3 * 32 + sl];
            u32 l0 = (u32)p0, h0 = (u32)(p0 >> 32);
            u32 l1 = (u32)p1, h1 = (u32)(p1 >> 32);
            u32 l2 = (u32)p2, h2 = (u32)(p2 >> 32);
            u32 l3 = (u32)p3, h3 = (u32)(p3 >> 32);
            a0 += bf2f(l0 & 0xffffu) + bf2f(l1 & 0xffffu) + bf2f(l2 & 0xffffu) + bf2f(l3 & 0xffffu);
            a1 += bf2f(l0 >> 16) + bf2f(l1 >> 16) + bf2f(l2 >> 16) + bf2f(l3 >> 16);
            a2 += bf2f(h0 & 0xffffu) + bf2f(h1 & 0xffffu) + bf2f(h2 & 0xffffu) + bf2f(h3 & 0xffffu);
            a3 += bf2f(h0 >> 16) + bf2f(h1 >> 16) + bf2f(h2 >> 16) + bf2f(h3 >> 16);
        }
        for (; j < cnt; ++j) {
            int c = __shfl(myc, j, 32);
            u64 p = X4[(size_t)c * 32 + sl];
            u32 lo = (u32)p, hi = (u32)(p >> 32);
            a0 += bf2f(lo & 0xffffu);
            a1 += bf2f(lo >> 16);
            a2 += bf2f(hi & 0xffffu);
            a3 += bf2f(hi >> 16);
        }
    }
    float s = inv_deg[row];
    a0 *= s; a1 *= s; a2 *= s; a3 *= s;
    // fragment store: u32 col u0 = 2*sl (even), u1 = u0+1 are adjacent (same cc,qq; jj,jj+1)
    int u0 = sl * 2;
    int cc = u0 >> 4, qq = (u0 >> 2) & 3, jj = u0 & 3;   // jj in {0,2}
    size_t dst = (size_t)(row >> 4) * 1024 + cc * 256 + qq * 64 + (row & 15) * 4 + jj;
    u64 sv = (u64)((u32)f2bf(a0) | ((u32)f2bf(a1) << 16))
           | ((u64)((u32)f2bf(a2) | ((u32)f2bf(a3) << 16)) << 32);
    *(u64*)(Sp + dst) = sv;   // 8B aligned: dst = 4k + {0,2}
    *(u64*)(Xp + dst) = px;
}

// ---------------- fused GEMM + attention combine; A = {S, X}; W = [Wl, -Wh, Wh, Wm] ----------------
// out_low = S@Wl, out_high = S@(-Wh) + X@Wh, out_mlp = X@Wm.
// R11: 8 waves/block, KPG=1 per wave. L1 (HOUT=128): 8 col-tiles x MT=4; L2 (HOUT=64): 4 col-tiles
// x 2 row-halves x MT=2. acc 48 VGPR (L1) vs 96 before -> no spill, 4-5 waves/SIMD residency.
// XCD swizzle matches k_spmm's so A-fragments are L2-local.
template<int HOUT, bool L1>
__global__ __launch_bounds__(512, 3)
void k_gemm_comb(const u16* __restrict__ Sp, const u16* __restrict__ Xp,
                 const u16* __restrict__ Wp,
                 const float* __restrict__ vl, const float* __restrict__ vh, const float* __restrict__ vm,
                 const float* __restrict__ att, int n,
                 u16* __restrict__ feaOut, float* __restrict__ fOut) {
    constexpr int WN = HOUT / 16;     // col-tile waves: 8 (L1) or 4 (L2)
    constexpr int WM = 8 / WN;        // row-half waves: 1 or 2
    constexpr int MT = 4 / WM;        // 16-row tiles per wave: 4 or 2
    constexpr int ROWS = 64;
    int w = threadIdx.x >> 6, lane = threadIdx.x & 63;
    int wn = w % WN, wm = w / WN;
    int ln15 = lane & 15, lq = lane >> 4;
    int m0 = xcd_swz(blockIdx.x, gridDim.x) * ROWS;

    f32x4 acc[MT][3];
#pragma unroll
    for (int mt = 0; mt < MT; ++mt)
#pragma unroll
        for (int g = 0; g < 3; ++g) { f32x4 z = {0.f, 0.f, 0.f, 0.f}; acc[mt][g] = z; }

#pragma unroll
    for (int c = 0; c < 4; ++c) {
        size_t fo = (size_t)(wn * 4 + c) * 512 + lane * 8;
        short8 bl  = *(const short8*)(Wp + (size_t)0 * (HOUT * 128) + fo);
        short8 bhn = *(const short8*)(Wp + (size_t)1 * (HOUT * 128) + fo);
        short8 bhp = *(const short8*)(Wp + (size_t)2 * (HOUT * 128) + fo);
        short8 bm  = *(const short8*)(Wp + (size_t)3 * (HOUT * 128) + fo);
#pragma unroll
        for (int mt = 0; mt < MT; ++mt) {
            int rt = wm * MT + mt;
            size_t off = ((size_t)((m0 >> 4) + rt) * 4 + c) * 512 + lane * 8;
            short8 as = *(const short8*)(Sp + off);
            short8 ax = *(const short8*)(Xp + off);
            acc[mt][0] = __builtin_amdgcn_mfma_f32_16x16x32_bf16(as, bl,  acc[mt][0], 0, 0, 0);
            acc[mt][1] = __builtin_amdgcn_mfma_f32_16x16x32_bf16(as, bhn, acc[mt][1], 0, 0, 0);
            acc[mt][1] = __builtin_amdgcn_mfma_f32_16x16x32_bf16(ax, bhp, acc[mt][1], 0, 0, 0);
            acc[mt][2] = __builtin_amdgcn_mfma_f32_16x16x32_bf16(ax, bm,  acc[mt][2], 0, 0, 0);
        }
    }

    int vcol = wn * 16 + ln15;
    float vv0 = vl[vcol], vv1 = vh[vcol], vv2 = vm[vcol];

    __shared__ float part[WN][3][ROWS];
    __shared__ float wgt[ROWS][3];
#pragma unroll
    for (int mt = 0; mt < MT; ++mt) {
        float pdg[3][4];
#pragma unroll
        for (int g = 0; g < 3; ++g)
#pragma unroll
            for (int r = 0; r < 4; ++r) pdg[g][r] = 0.f;
#pragma unroll
        for (int r = 0; r < 4; ++r) {
            pdg[0][r] += fmaxf(acc[mt][0][r], 0.f) * vv0;
            pdg[1][r] += fmaxf(acc[mt][1][r], 0.f) * vv1;
            pdg[2][r] += fmaxf(acc[mt][2][r], 0.f) * vv2;
        }
#pragma unroll
        for (int off = 1; off < 16; off <<= 1)
#pragma unroll
            for (int g = 0; g < 3; ++g)
#pragma unroll
                for (int r = 0; r < 4; ++r)
                    pdg[g][r] += __shfl_xor(pdg[g][r], off);
        if (ln15 == 0) {
            int rbase = (wm * MT + mt) * 16 + lq * 4;
#pragma unroll
            for (int g = 0; g < 3; ++g)
#pragma unroll
                for (int r = 0; r < 4; ++r)
                    part[wn][g][rbase + r] = pdg[g][r];
        }
    }
    __syncthreads();
    if (threadIdx.x < ROWS) {
        int row = threadIdx.x;
        float d0 = 0.f, d1 = 0.f, d2 = 0.f;
#pragma unroll
        for (int q = 0; q < WN; ++q) {
            d0 += part[q][0][row];
            d1 += part[q][1][row];
            d2 += part[q][2][row];
        }
        float s0 = 1.f / (1.f + __expf(-d0));
        float s1 = 1.f / (1.f + __expf(-d1));
        float s2 = 1.f / (1.f + __expf(-d2));
        float a0 = (s0 * att[0] + s1 * att[3] + s2 * att[6]) * (1.f / 3.f);
        float a1 = (s0 * att[1] + s1 * att[4] + s2 * att[7]) * (1.f / 3.f);
        float a2 = (s0 * att[2] + s1 * att[5] + s2 * att[8]) * (1.f / 3.f);
        float mx = fmaxf(a0, fmaxf(a1, a2));
        float e0 = __expf(a0 - mx), e1 = __expf(a1 - mx), e2 = __expf(a2 - mx);
        float inv = 3.f / (e0 + e1 + e2);
        wgt[row][0] = e0 * inv;
        wgt[row][1] = e1 * inv;
        wgt[row][2] = e2 * inv;
    }
    __syncthreads();

#pragma unroll
    for (int mt = 0; mt < MT; ++mt)
#pragma unroll
        for (int r = 0; r < 4; ++r) {
            int row_local = (wm * MT + mt) * 16 + lq * 4 + r;
            int row = m0 + row_local;
            if (row < n) {
                int col = wn * 16 + ln15;
                float w0 = wgt[row_local][0], w1 = wgt[row_local][1], w2 = wgt[row_local][2];
                float ol = fmaxf(acc[mt][0][r], 0.f);
                float oh = fmaxf(acc[mt][1][r], 0.f);
                float om = fmaxf(acc[mt][2][r], 0.f);
                float val = w0 * ol + w1 * oh + w2 * om;
                if (L1)
                    feaOut[(size_t)row * HOUT + col] = f2bf(fmaxf(val, 0.f));
                else
                    fOut[(size_t)row * HOUT + col] = val;
            }
        }
}

extern "C" void kernel_launch(void* const* d_in, const int* in_sizes, int n_in,
                              void* d_out, int out_size, void* d_ws, size_t ws_size,
                              hipStream_t stream) {
    const int F = 128;
    int n = in_sizes[0] / F;
    int e = in_sizes[1] / 2;
    int n64 = (n + 63) & ~63;
    int nbuck = (n + (1 << BSHIFT) - 1) >> BSHIFT;
    const float* x = (const float*)d_in[0];
    const int* ei = (const int*)d_in[1];
    const int* erow = ei;
    const int* ecol = ei + e;
    const float *Wl1 = (const float*)d_in[2], *Wh1 = (const float*)d_in[3], *Wm1 = (const float*)d_in[4];
    const float *vl1 = (const float*)d_in[5], *vh1 = (const float*)d_in[6], *vm1 = (const float*)d_in[7];
    const float* att1 = (const float*)d_in[8];
    const float *Wl2 = (const float*)d_in[9], *Wh2 = (const float*)d_in[10], *Wm2 = (const float*)d_in[11];
    const float *vl2 = (const float*)d_in[12], *vh2 = (const float*)d_in[13], *vm2 = (const float*)d_in[14];
    const float* att2 = (const float*)d_in[15];
    float* out = (float*)d_out;

    char* ws = (char*)d_ws;
    size_t off = 0;
    auto alloc = [&](size_t b) -> void* {
        void* p = ws + off;
        off = (off + b + 255) & ~(size_t)255;
        return p;
    };
    int* deg = (int*)alloc((size_t)n * 4);
    int* row_ptr = (int*)alloc((size_t)(n + 1) * 4);
    float* inv_deg = (float*)alloc((size_t)n * 4);
    int* bsum = (int*)alloc(1024);
    int* boff = (int*)alloc(1024);
    int* gcursor = (int*)alloc(MAXBUCK * 4);
    u32* bedge = (u32*)alloc((size_t)e * 4);
    int* cols = (int*)alloc((size_t)e * 4);
    u32* Sp = (u32*)alloc((size_t)n64 * 64 * 4);
    u32* Xp = (u32*)alloc((size_t)n64 * 64 * 4);
    u32* Fp = (u32*)alloc((size_t)n64 * 64 * 4);
    u16* Xb = (u16*)alloc((size_t)n * 128 * 2);
    u16* fea = (u16*)alloc((size_t)n * 128 * 2);
    u16* Wp1 = (u16*)alloc((size_t)4 * 128 * 128 * 2);
    u16* Wp2 = (u16*)alloc((size_t)4 * 64 * 128 * 2);
    (void)ws_size; (void)n_in; (void)out_size;

    const int tb = 256;
    k_prep<<<CASTBLK + 16, 256, 0, stream>>>((const float4*)x, (u32*)Xb, (long)n * 32,
                                             Wl1, Wh1, Wm1, Wl2, Wh2, Wm2, Wp1, Wp2);

    hipMemsetAsync(deg, 0, (size_t)n * 4, stream);
    k_deg<<<(e + tb - 1) / tb, tb, 0, stream>>>(erow, e, deg);
    int nb = (n + 1023) / 1024;
    k_scan_a<<<nb, 256, 0, stream>>>(deg, n, bsum);
    k_scan_b<<<1, 256, 0, stream>>>(bsum, nb, boff);
    k_scan_c<<<nb, 256, 0, stream>>>(deg, n, boff, row_ptr, inv_deg, gcursor);

    k_bscatter<<<256, 256, 0, stream>>>(erow, ecol, e, nbuck, gcursor, bedge);
    k_bfill<<<nbuck, 256, 0, stream>>>(bedge, row_ptr, n, cols);

    int wb = (n + 7) / 8;      // 4 waves/block x 2 rows/wave = 8 rows/block
    int gb = n64 / 64;

    // layer 1
    k_spmm<<<wb, 256, 0, stream>>>((const u32*)Xb, row_ptr, cols, inv_deg, Sp, Xp, n);
    k_gemm_comb<128, true><<<gb, 512, 0, stream>>>((const u16*)Sp, (const u16*)Xp,
                                                   Wp1, vl1, vh1, vm1, att1, n, fea, nullptr);

    // layer 2
    k_spmm<<<wb, 256, 0, stream>>>((const u32*)fea, row_ptr, cols, inv_deg, Sp, Fp, n);
    k_gemm_comb<64, false><<<gb, 512, 0, stream>>>((const u16*)Sp, (const u16*)Fp,
                                                   Wp2, vl2, vh2, vm2, att2, n, nullptr, out);
}

// Round 3
// 403.356 us; speedup vs baseline: 1.1798x; 1.1494x over previous
//
#include <hip/hip_runtime.h>

typedef unsigned short u16;
typedef unsigned int u32;
typedef unsigned long long u64;
typedef __attribute__((ext_vector_type(8))) short short8;
typedef __attribute__((ext_vector_type(4))) float f32x4;

#define BSHIFT 8               // 256 rows per bucket
#define MAXBUCK 512

__device__ __forceinline__ float bf2f(u32 u) {
    union { u32 i; float f; } v; v.i = u << 16; return v.f;
}
__device__ __forceinline__ u16 f2bf(float f) {
    union { float f; u32 i; } v; v.f = f;
    u32 u = (v.i + 0x7fffu + ((v.i >> 16) & 1u)) >> 16;
    return (u16)u;
}

// bijective XCD-chunked swizzle (m204 form): contiguous row ranges live on one XCD in BOTH
// producer (spmm) and consumer (gemm) grids.
__device__ __forceinline__ int xcd_swz(int bid, int nbg) {
    int q = nbg >> 3, r = nbg & 7;
    int x = bid & 7, i = bid >> 3;
    return (x < r) ? (x * (q + 1) + i) : (r * (q + 1) + (x - r) * q + i);
}

// ---------------- fused: cast x -> bf16 row-major  +  pack weights (with -Wh copy) ----------------
// W pack layout per layer: 4 matrices [Wl, -Wh, Wh, Wm], each MFMA-B-fragment packed:
// u16 idx = (T*4 + c)*512 + lane*8 + j ; col = T*16 + (lane&15), k = c*32 + (lane>>4)*8 + j.
#define CASTBLK 2048
__global__ void k_prep(const float4* __restrict__ X, u32* __restrict__ Xb, long total4,
                       const float* __restrict__ Wl1, const float* __restrict__ Wh1,
                       const float* __restrict__ Wm1, const float* __restrict__ Wl2,
                       const float* __restrict__ Wh2, const float* __restrict__ Wm2,
                       u16* __restrict__ Wp1, u16* __restrict__ Wp2) {
    if (blockIdx.x < CASTBLK) {
        long i = (long)blockIdx.x * blockDim.x + threadIdx.x;
        long stride = (long)CASTBLK * blockDim.x;
        for (; i < total4; i += stride) {
            float4 p = X[i];
            Xb[i * 2 + 0] = (u32)f2bf(p.x) | ((u32)f2bf(p.y) << 16);
            Xb[i * 2 + 1] = (u32)f2bf(p.z) | ((u32)f2bf(p.w) << 16);
        }
        return;
    }
    int tid = (blockIdx.x - CASTBLK) * blockDim.x + threadIdx.x;
    int nthr = 16 * blockDim.x;
    for (int m = 0; m < 8; ++m) {
        int layer = m >> 2;          // 0: L1, 1: L2
        int slot = m & 3;            // 0 Wl, 1 -Wh, 2 Wh, 3 Wm
        int Hout = layer ? 64 : 128;
        const float* W = layer ? (slot == 0 ? Wl2 : (slot == 3 ? Wm2 : Wh2))
                               : (slot == 0 ? Wl1 : (slot == 3 ? Wm1 : Wh1));
        float sgn = (slot == 1) ? -1.f : 1.f;
        u16* dst = (layer ? Wp2 : Wp1) + slot * Hout * 128;
        int total = 128 * Hout;
        for (int i = tid; i < total; i += nthr) {
            int T = i / 2048;
            int c = (i / 512) & 3;
            int lane = (i / 8) & 63;
            int j = i & 7;
            int col = T * 16 + (lane & 15);
            int k = c * 32 + (lane >> 4) * 8 + j;
            dst[i] = f2bf(sgn * W[k * Hout + col]);
        }
    }
}

// ---------------- CSR build, bucket-first (R12): no global degree atomics ----------------
// 1) k_bhist: per-block LDS bucket histogram -> aggregated global adds (~100k, not 1.6M)
__global__ void k_bhist(const int* __restrict__ erow, int e, int nbuck, int* __restrict__ bcnt) {
    __shared__ int hist[MAXBUCK];
    for (int t = threadIdx.x; t < nbuck; t += blockDim.x) hist[t] = 0;
    __syncthreads();
    int chunk = (e + gridDim.x - 1) / gridDim.x;
    int lo = blockIdx.x * chunk, hi = min(e, lo + chunk);
    for (int i = lo + threadIdx.x; i < hi; i += blockDim.x)
        atomicAdd(&hist[erow[i] >> BSHIFT], 1);
    __syncthreads();
    for (int t = threadIdx.x; t < nbuck; t += blockDim.x)
        if (hist[t]) atomicAdd(&bcnt[t], hist[t]);
}

// 2) single-block scan of bucket counts -> boff[0..nbuck] and gcursor init
__global__ void k_bscan(const int* __restrict__ bcnt, int nbuck, int* __restrict__ boff,
                        int* __restrict__ gcursor) {
    __shared__ int lds[MAXBUCK];
    int t = threadIdx.x;
    int v = (t < nbuck) ? bcnt[t] : 0;
    lds[t] = v; __syncthreads();
    for (int off = 1; off < MAXBUCK; off <<= 1) {
        int x = (t >= off) ? lds[t - off] : 0;
        __syncthreads();
        lds[t] += x;
        __syncthreads();
    }
    if (t < nbuck) {
        int ex = lds[t] - v;
        boff[t] = ex;
        gcursor[t] = ex;
        if (t == nbuck - 1) boff[nbuck] = lds[t];
    }
}

// 3) bucketed edge scatter; bedge packed u32 = (col<<8) | (row & 255)
__global__ void k_bscatter(const int* __restrict__ erow, const int* __restrict__ ecol, int e,
                           int nbuck, int* __restrict__ gcursor, u32* __restrict__ bedge) {
    __shared__ int hist[MAXBUCK];
    __shared__ int base[MAXBUCK];
    for (int t = threadIdx.x; t < nbuck; t += blockDim.x) hist[t] = 0;
    __syncthreads();
    int chunk = (e + gridDim.x - 1) / gridDim.x;
    int lo = blockIdx.x * chunk, hi = min(e, lo + chunk);
    for (int i = lo + threadIdx.x; i < hi; i += blockDim.x)
        atomicAdd(&hist[erow[i] >> BSHIFT], 1);
    __syncthreads();
    for (int t = threadIdx.x; t < nbuck; t += blockDim.x) {
        int c = hist[t];
        base[t] = c ? atomicAdd(&gcursor[t], c) : 0;
        hist[t] = 0;
    }
    __syncthreads();
    for (int i = lo + threadIdx.x; i < hi; i += blockDim.x) {
        int r = erow[i];
        int bk = r >> BSHIFT;
        int pos = base[bk] + atomicAdd(&hist[bk], 1);
        bedge[pos] = ((u32)ecol[i] << 8) | (u32)(r & 255);
    }
}

// 4) per-bucket: LDS degree count + LDS scan -> row_ptr/inv_deg, then cols scatter.
//    Replaces k_deg (1.6M global atomics, 66us) + k_scan_a/b/c entirely.
__global__ void k_bfill2(const u32* __restrict__ bedge, const int* __restrict__ boff, int n,
                         int* __restrict__ row_ptr, float* __restrict__ inv_deg,
                         int* __restrict__ cols) {
    __shared__ int cnt[256];
    __shared__ int incl[256];
    __shared__ int pos[256];
    int b = blockIdx.x, t = threadIdx.x;
    cnt[t] = 0;
    __syncthreads();
    int rbase = b << BSHIFT;
    int lo = boff[b], hi = boff[b + 1];
    for (int i = lo + t; i < hi; i += 256)
        atomicAdd(&cnt[bedge[i] & 255u], 1);
    __syncthreads();
    int v = cnt[t];
    incl[t] = v;
    __syncthreads();
    for (int off = 1; off < 256; off <<= 1) {
        int x = (t >= off) ? incl[t - off] : 0;
        __syncthreads();
        incl[t] += x;
        __syncthreads();
    }
    int excl = incl[t] - v;
    pos[t] = excl;
    int row = rbase + t;
    if (row < n) {
        row_ptr[row] = lo + excl;
        inv_deg[row] = v > 0 ? 1.f / (float)v : 0.f;
    }
    if (b == (int)gridDim.x - 1 && t == 0) row_ptr[n] = hi;
    __syncthreads();
    for (int i = lo + t; i < hi; i += 256) {
        u32 vv = bedge[i];
        int rl = (int)(vv & 255u);
        int p = lo + atomicAdd(&pos[rl], 1);
        cols[p] = (int)(vv >> 8);
    }
}

// ---------------- SpMM: bf16 X row-major in; A-fragment-packed S (=adj@X scaled) and X out ----------------
// R10: 2 rows per wave (32-lane halves), u64 gathers. R11: XCD swizzle matched with gemm.
__global__ void k_spmm(const u32* __restrict__ X2, const int* __restrict__ row_ptr,
                       const int* __restrict__ cols, const float* __restrict__ inv_deg,
                       u32* __restrict__ Sp, u32* __restrict__ Xp, int n) {
    int blk = xcd_swz(blockIdx.x, gridDim.x);
    int wave = blk * 4 + (int)(threadIdx.x >> 6);
    int lane = threadIdx.x & 63;
    int sl = lane & 31;                 // lane within half
    int row = wave * 2 + (lane >> 5);   // half 0 -> even row, half 1 -> odd row
    if (row >= n) return;
    const u64* X4 = (const u64*)X2;     // lane sl covers u32 cols {2sl, 2sl+1} = 4 bf16
    int beg = row_ptr[row], end = row_ptr[row + 1];
    u64 px = X4[(size_t)row * 32 + sl]; // self row, issued early to overlap gather loop
    float a0 = 0.f, a1 = 0.f, a2 = 0.f, a3 = 0.f;
    for (int j0 = beg; j0 < end; j0 += 32) {
        int cnt = end - j0; if (cnt > 32) cnt = 32;
        int myc = (sl < cnt) ? cols[j0 + sl] : 0;
        int j = 0;
        for (; j + 8 <= cnt; j += 8) {
            int c0 = __shfl(myc, j + 0, 32);
            int c1 = __shfl(myc, j + 1, 32);
            int c2 = __shfl(myc, j + 2, 32);
            int c3 = __shfl(myc, j + 3, 32);
            int c4 = __shfl(myc, j + 4, 32);
            int c5 = __shfl(myc, j + 5, 32);
            int c6 = __shfl(myc, j + 6, 32);
            int c7 = __shfl(myc, j + 7, 32);
            u64 p0 = X4[(size_t)c0 * 32 + sl];
            u64 p1 = X4[(size_t)c1 * 32 + sl];
            u64 p2 = X4[(size_t)c2 * 32 + sl];
            u64 p3 = X4[(size_t)c3 * 32 + sl];
            u64 p4 = X4[(size_t)c4 * 32 + sl];
            u64 p5 = X4[(size_t)c5 * 32 + sl];
            u64 p6 = X4[(size_t)c6 * 32 + sl];
            u64 p7 = X4[(size_t)c7 * 32 + sl];
            u32 l0 = (u32)p0, h0 = (u32)(p0 >> 32);
            u32 l1 = (u32)p1, h1 = (u32)(p1 >> 32);
            u32 l2 = (u32)p2, h2 = (u32)(p2 >> 32);
            u32 l3 = (u32)p3, h3 = (u32)(p3 >> 32);
            u32 l4 = (u32)p4, h4 = (u32)(p4 >> 32);
            u32 l5 = (u32)p5, h5 = (u32)(p5 >> 32);
            u32 l6 = (u32)p6, h6 = (u32)(p6 >> 32);
            u32 l7 = (u32)p7, h7 = (u32)(p7 >> 32);
            a0 += bf2f(l0 & 0xffffu) + bf2f(l1 & 0xffffu) + bf2f(l2 & 0xffffu) + bf2f(l3 & 0xffffu)
                + bf2f(l4 & 0xffffu) + bf2f(l5 & 0xffffu) + bf2f(l6 & 0xffffu) + bf2f(l7 & 0xffffu);
            a1 += bf2f(l0 >> 16) + bf2f(l1 >> 16) + bf2f(l2 >> 16) + bf2f(l3 >> 16)
                + bf2f(l4 >> 16) + bf2f(l5 >> 16) + bf2f(l6 >> 16) + bf2f(l7 >> 16);
            a2 += bf2f(h0 & 0xffffu) + bf2f(h1 & 0xffffu) + bf2f(h2 & 0xffffu) + bf2f(h3 & 0xffffu)
                + bf2f(h4 & 0xffffu) + bf2f(h5 & 0xffffu) + bf2f(h6 & 0xffffu) + bf2f(h7 & 0xffffu);
            a3 += bf2f(h0 >> 16) + bf2f(h1 >> 16) + bf2f(h2 >> 16) + bf2f(h3 >> 16)
                + bf2f(h4 >> 16) + bf2f(h5 >> 16) + bf2f(h6 >> 16) + bf2f(h7 >> 16);
        }
        for (; j + 4 <= cnt; j += 4) {
            int c0 = __shfl(myc, j + 0, 32);
            int c1 = __shfl(myc, j + 1, 32);
            int c2 = __shfl(myc, j + 2, 32);
            int c3 = __shfl(myc, j + 3, 32);
            u64 p0 = X4[(size_t)c0 * 32 + sl];
            u64 p1 = X4[(size_t)c1 * 32 + sl];
            u64 p2 = X4[(size_t)c2 * 32 + sl];
            u64 p3 = X4[(size_t)c3 * 32 + sl];
            u32 l0 = (u32)p0, h0 = (u32)(p0 >> 32);
            u32 l1 = (u32)p1, h1 = (u32)(p1 >> 32);
            u32 l2 = (u32)p2, h2 = (u32)(p2 >> 32);
            u32 l3 = (u32)p3, h3 = (u32)(p3 >> 32);
            a0 += bf2f(l0 & 0xffffu) + bf2f(l1 & 0xffffu) + bf2f(l2 & 0xffffu) + bf2f(l3 & 0xffffu);
            a1 += bf2f(l0 >> 16) + bf2f(l1 >> 16) + bf2f(l2 >> 16) + bf2f(l3 >> 16);
            a2 += bf2f(h0 & 0xffffu) + bf2f(h1 & 0xffffu) + bf2f(h2 & 0xffffu) + bf2f(h3 & 0xffffu);
            a3 += bf2f(h0 >> 16) + bf2f(h1 >> 16) + bf2f(h2 >> 16) + bf2f(h3 >> 16);
        }
        for (; j < cnt; ++j) {
            int c = __shfl(myc, j, 32);
            u64 p = X4[(size_t)c * 32 + sl];
            u32 lo = (u32)p, hi = (u32)(p >> 32);
            a0 += bf2f(lo & 0xffffu);
            a1 += bf2f(lo >> 16);
            a2 += bf2f(hi & 0xffffu);
            a3 += bf2f(hi >> 16);
        }
    }
    float s = inv_deg[row];
    a0 *= s; a1 *= s; a2 *= s; a3 *= s;
    // fragment store: u32 col u0 = 2*sl (even), u1 = u0+1 are adjacent (same cc,qq; jj,jj+1)
    int u0 = sl * 2;
    int cc = u0 >> 4, qq = (u0 >> 2) & 3, jj = u0 & 3;   // jj in {0,2}
    size_t dst = (size_t)(row >> 4) * 1024 + cc * 256 + qq * 64 + (row & 15) * 4 + jj;
    u64 sv = (u64)((u32)f2bf(a0) | ((u32)f2bf(a1) << 16))
           | ((u64)((u32)f2bf(a2) | ((u32)f2bf(a3) << 16)) << 32);
    *(u64*)(Sp + dst) = sv;   // 8B aligned: dst = 4k + {0,2}
    *(u64*)(Xp + dst) = px;
}

// ---------------- fused GEMM + attention combine; A = {S, X}; W = [Wl, -Wh, Wh, Wm] ----------------
// out_low = S@Wl, out_high = S@(-Wh) + X@Wh, out_mlp = X@Wm.
// R11: 8 waves/block, KPG=1 per wave. L1 (HOUT=128): 8 col-tiles x MT=4; L2 (HOUT=64): 4 col-tiles
// x 2 row-halves x MT=2. XCD swizzle matches k_spmm's so A-fragments are L2-local.
template<int HOUT, bool L1>
__global__ __launch_bounds__(512, 3)
void k_gemm_comb(const u16* __restrict__ Sp, const u16* __restrict__ Xp,
                 const u16* __restrict__ Wp,
                 const float* __restrict__ vl, const float* __restrict__ vh, const float* __restrict__ vm,
                 const float* __restrict__ att, int n,
                 u16* __restrict__ feaOut, float* __restrict__ fOut) {
    constexpr int WN = HOUT / 16;     // col-tile waves: 8 (L1) or 4 (L2)
    constexpr int WM = 8 / WN;        // row-half waves: 1 or 2
    constexpr int MT = 4 / WM;        // 16-row tiles per wave: 4 or 2
    constexpr int ROWS = 64;
    int w = threadIdx.x >> 6, lane = threadIdx.x & 63;
    int wn = w % WN, wm = w / WN;
    int ln15 = lane & 15, lq = lane >> 4;
    int m0 = xcd_swz(blockIdx.x, gridDim.x) * ROWS;

    f32x4 acc[MT][3];
#pragma unroll
    for (int mt = 0; mt < MT; ++mt)
#pragma unroll
        for (int g = 0; g < 3; ++g) { f32x4 z = {0.f, 0.f, 0.f, 0.f}; acc[mt][g] = z; }

#pragma unroll
    for (int c = 0; c < 4; ++c) {
        size_t fo = (size_t)(wn * 4 + c) * 512 + lane * 8;
        short8 bl  = *(const short8*)(Wp + (size_t)0 * (HOUT * 128) + fo);
        short8 bhn = *(const short8*)(Wp + (size_t)1 * (HOUT * 128) + fo);
        short8 bhp = *(const short8*)(Wp + (size_t)2 * (HOUT * 128) + fo);
        short8 bm  = *(const short8*)(Wp + (size_t)3 * (HOUT * 128) + fo);
#pragma unroll
        for (int mt = 0; mt < MT; ++mt) {
            int rt = wm * MT + mt;
            size_t off = ((size_t)((m0 >> 4) + rt) * 4 + c) * 512 + lane * 8;
            short8 as = *(const short8*)(Sp + off);
            short8 ax = *(const short8*)(Xp + off);
            acc[mt][0] = __builtin_amdgcn_mfma_f32_16x16x32_bf16(as, bl,  acc[mt][0], 0, 0, 0);
            acc[mt][1] = __builtin_amdgcn_mfma_f32_16x16x32_bf16(as, bhn, acc[mt][1], 0, 0, 0);
            acc[mt][1] = __builtin_amdgcn_mfma_f32_16x16x32_bf16(ax, bhp, acc[mt][1], 0, 0, 0);
            acc[mt][2] = __builtin_amdgcn_mfma_f32_16x16x32_bf16(ax, bm,  acc[mt][2], 0, 0, 0);
        }
    }

    int vcol = wn * 16 + ln15;
    float vv0 = vl[vcol], vv1 = vh[vcol], vv2 = vm[vcol];

    __shared__ float part[WN][3][ROWS];
    __shared__ float wgt[ROWS][3];
#pragma unroll
    for (int mt = 0; mt < MT; ++mt) {
        float pdg[3][4];
#pragma unroll
        for (int g = 0; g < 3; ++g)
#pragma unroll
            for (int r = 0; r < 4; ++r) pdg[g][r] = 0.f;
#pragma unroll
        for (int r = 0; r < 4; ++r) {
            pdg[0][r] += fmaxf(acc[mt][0][r], 0.f) * vv0;
            pdg[1][r] += fmaxf(acc[mt][1][r], 0.f) * vv1;
            pdg[2][r] += fmaxf(acc[mt][2][r], 0.f) * vv2;
        }
#pragma unroll
        for (int off = 1; off < 16; off <<= 1)
#pragma unroll
            for (int g = 0; g < 3; ++g)
#pragma unroll
                for (int r = 0; r < 4; ++r)
                    pdg[g][r] += __shfl_xor(pdg[g][r], off);
        if (ln15 == 0) {
            int rbase = (wm * MT + mt) * 16 + lq * 4;
#pragma unroll
            for (int g = 0; g < 3; ++g)
#pragma unroll
                for (int r = 0; r < 4; ++r)
                    part[wn][g][rbase + r] = pdg[g][r];
        }
    }
    __syncthreads();
    if (threadIdx.x < ROWS) {
        int row = threadIdx.x;
        float d0 = 0.f, d1 = 0.f, d2 = 0.f;
#pragma unroll
        for (int q = 0; q < WN; ++q) {
            d0 += part[q][0][row];
            d1 += part[q][1][row];
            d2 += part[q][2][row];
        }
        float s0 = 1.f / (1.f + __expf(-d0));
        float s1 = 1.f / (1.f + __expf(-d1));
        float s2 = 1.f / (1.f + __expf(-d2));
        float a0 = (s0 * att[0] + s1 * att[3] + s2 * att[6]) * (1.f / 3.f);
        float a1 = (s0 * att[1] + s1 * att[4] + s2 * att[7]) * (1.f / 3.f);
        float a2 = (s0 * att[2] + s1 * att[5] + s2 * att[8]) * (1.f / 3.f);
        float mx = fmaxf(a0, fmaxf(a1, a2));
        float e0 = __expf(a0 - mx), e1 = __expf(a1 - mx), e2 = __expf(a2 - mx);
        float inv = 3.f / (e0 + e1 + e2);
        wgt[row][0] = e0 * inv;
        wgt[row][1] = e1 * inv;
        wgt[row][2] = e2 * inv;
    }
    __syncthreads();

#pragma unroll
    for (int mt = 0; mt < MT; ++mt)
#pragma unroll
        for (int r = 0; r < 4; ++r) {
            int row_local = (wm * MT + mt) * 16 + lq * 4 + r;
            int row = m0 + row_local;
            if (row < n) {
                int col = wn * 16 + ln15;
                float w0 = wgt[row_local][0], w1 = wgt[row_local][1], w2 = wgt[row_local][2];
                float ol = fmaxf(acc[mt][0][r], 0.f);
                float oh = fmaxf(acc[mt][1][r], 0.f);
                float om = fmaxf(acc[mt][2][r], 0.f);
                float val = w0 * ol + w1 * oh + w2 * om;
                if (L1)
                    feaOut[(size_t)row * HOUT + col] = f2bf(fmaxf(val, 0.f));
                else
                    fOut[(size_t)row * HOUT + col] = val;
            }
        }
}

extern "C" void kernel_launch(void* const* d_in, const int* in_sizes, int n_in,
                              void* d_out, int out_size, void* d_ws, size_t ws_size,
                              hipStream_t stream) {
    const int F = 128;
    int n = in_sizes[0] / F;
    int e = in_sizes[1] / 2;
    int n64 = (n + 63) & ~63;
    int nbuck = (n + (1 << BSHIFT) - 1) >> BSHIFT;
    const float* x = (const float*)d_in[0];
    const int* ei = (const int*)d_in[1];
    const int* erow = ei;
    const int* ecol = ei + e;
    const float *Wl1 = (const float*)d_in[2], *Wh1 = (const float*)d_in[3], *Wm1 = (const float*)d_in[4];
    const float *vl1 = (const float*)d_in[5], *vh1 = (const float*)d_in[6], *vm1 = (const float*)d_in[7];
    const float* att1 = (const float*)d_in[8];
    const float *Wl2 = (const float*)d_in[9], *Wh2 = (const float*)d_in[10], *Wm2 = (const float*)d_in[11];
    const float *vl2 = (const float*)d_in[12], *vh2 = (const float*)d_in[13], *vm2 = (const float*)d_in[14];
    const float* att2 = (const float*)d_in[15];
    float* out = (float*)d_out;

    char* ws = (char*)d_ws;
    size_t off = 0;
    auto alloc = [&](size_t b) -> void* {
        void* p = ws + off;
        off = (off + b + 255) & ~(size_t)255;
        return p;
    };
    int* row_ptr = (int*)alloc((size_t)(n + 1) * 4);
    float* inv_deg = (float*)alloc((size_t)n * 4);
    int* bcnt = (int*)alloc(MAXBUCK * 4);
    int* boff = (int*)alloc((MAXBUCK + 1) * 4);
    int* gcursor = (int*)alloc(MAXBUCK * 4);
    u32* bedge = (u32*)alloc((size_t)e * 4);
    int* cols = (int*)alloc((size_t)e * 4);
    u32* Sp = (u32*)alloc((size_t)n64 * 64 * 4);
    u32* Xp = (u32*)alloc((size_t)n64 * 64 * 4);
    u32* Fp = (u32*)alloc((size_t)n64 * 64 * 4);
    u16* Xb = (u16*)alloc((size_t)n * 128 * 2);
    u16* fea = (u16*)alloc((size_t)n * 128 * 2);
    u16* Wp1 = (u16*)alloc((size_t)4 * 128 * 128 * 2);
    u16* Wp2 = (u16*)alloc((size_t)4 * 64 * 128 * 2);
    (void)ws_size; (void)n_in; (void)out_size;

    k_prep<<<CASTBLK + 16, 256, 0, stream>>>((const float4*)x, (u32*)Xb, (long)n * 32,
                                             Wl1, Wh1, Wm1, Wl2, Wh2, Wm2, Wp1, Wp2);

    hipMemsetAsync(bcnt, 0, (size_t)MAXBUCK * 4, stream);
    k_bhist<<<256, 256, 0, stream>>>(erow, e, nbuck, bcnt);
    k_bscan<<<1, MAXBUCK, 0, stream>>>(bcnt, nbuck, boff, gcursor);
    k_bscatter<<<256, 256, 0, stream>>>(erow, ecol, e, nbuck, gcursor, bedge);
    k_bfill2<<<nbuck, 256, 0, stream>>>(bedge, boff, n, row_ptr, inv_deg, cols);

    int wb = (n + 7) / 8;      // 4 waves/block x 2 rows/wave = 8 rows/block
    int gb = n64 / 64;

    // layer 1
    k_spmm<<<wb, 256, 0, stream>>>((const u32*)Xb, row_ptr, cols, inv_deg, Sp, Xp, n);
    k_gemm_comb<128, true><<<gb, 512, 0, stream>>>((const u16*)Sp, (const u16*)Xp,
                                                   Wp1, vl1, vh1, vm1, att1, n, fea, nullptr);

    // layer 2
    k_spmm<<<wb, 256, 0, stream>>>((const u32*)fea, row_ptr, cols, inv_deg, Sp, Fp, n);
    k_gemm_comb<64, false><<<gb, 512, 0, stream>>>((const u16*)Sp, (const u16*)Fp,
                                                   Wp2, vl2, vh2, vm2, att2, n, nullptr, out);
}

// Round 4
// 397.101 us; speedup vs baseline: 1.1984x; 1.0158x over previous
//
#include <hip/hip_runtime.h>

typedef unsigned short u16;
typedef unsigned int u32;
typedef unsigned long long u64;
typedef __attribute__((ext_vector_type(8))) short short8;
typedef __attribute__((ext_vector_type(4))) float f32x4;

#define BSHIFT 8               // 256 rows per bucket
#define MAXBUCK 512

__device__ __forceinline__ float bf2f(u32 u) {
    union { u32 i; float f; } v; v.i = u << 16; return v.f;
}
__device__ __forceinline__ u16 f2bf(float f) {
    union { float f; u32 i; } v; v.f = f;
    u32 u = (v.i + 0x7fffu + ((v.i >> 16) & 1u)) >> 16;
    return (u16)u;
}

// async global->LDS DMA, 16B per lane. LDS dest is wave-uniform base (+lane*16 applied by HW);
// global src is per-lane.
__device__ __forceinline__ void gload_lds16(const void* g, void* l) {
    __builtin_amdgcn_global_load_lds(
        (const __attribute__((address_space(1))) unsigned int*)g,
        (__attribute__((address_space(3))) unsigned int*)l, 16, 0, 0);
}

// bijective XCD-chunked swizzle (m204 form): contiguous row ranges live on one XCD in BOTH
// producer (spmm) and consumer (gemm) grids.
__device__ __forceinline__ int xcd_swz(int bid, int nbg) {
    int q = nbg >> 3, r = nbg & 7;
    int x = bid & 7, i = bid >> 3;
    return (x < r) ? (x * (q + 1) + i) : (r * (q + 1) + (x - r) * q + i);
}

// ---------------- fused: cast x -> bf16 row-major  +  pack weights (with -Wh copy) ----------------
// W pack layout per layer: 4 matrices [Wl, -Wh, Wh, Wm], each MFMA-B-fragment packed:
// u16 idx = (T*4 + c)*512 + lane*8 + j ; col = T*16 + (lane&15), k = c*32 + (lane>>4)*8 + j.
#define CASTBLK 2048
__global__ void k_prep(const float4* __restrict__ X, u32* __restrict__ Xb, long total4,
                       const float* __restrict__ Wl1, const float* __restrict__ Wh1,
                       const float* __restrict__ Wm1, const float* __restrict__ Wl2,
                       const float* __restrict__ Wh2, const float* __restrict__ Wm2,
                       u16* __restrict__ Wp1, u16* __restrict__ Wp2) {
    if (blockIdx.x < CASTBLK) {
        long i = (long)blockIdx.x * blockDim.x + threadIdx.x;
        long stride = (long)CASTBLK * blockDim.x;
        for (; i < total4; i += stride) {
            float4 p = X[i];
            Xb[i * 2 + 0] = (u32)f2bf(p.x) | ((u32)f2bf(p.y) << 16);
            Xb[i * 2 + 1] = (u32)f2bf(p.z) | ((u32)f2bf(p.w) << 16);
        }
        return;
    }
    int tid = (blockIdx.x - CASTBLK) * blockDim.x + threadIdx.x;
    int nthr = 16 * blockDim.x;
    for (int m = 0; m < 8; ++m) {
        int layer = m >> 2;          // 0: L1, 1: L2
        int slot = m & 3;            // 0 Wl, 1 -Wh, 2 Wh, 3 Wm
        int Hout = layer ? 64 : 128;
        const float* W = layer ? (slot == 0 ? Wl2 : (slot == 3 ? Wm2 : Wh2))
                               : (slot == 0 ? Wl1 : (slot == 3 ? Wm1 : Wh1));
        float sgn = (slot == 1) ? -1.f : 1.f;
        u16* dst = (layer ? Wp2 : Wp1) + slot * Hout * 128;
        int total = 128 * Hout;
        for (int i = tid; i < total; i += nthr) {
            int T = i / 2048;
            int c = (i / 512) & 3;
            int lane = (i / 8) & 63;
            int j = i & 7;
            int col = T * 16 + (lane & 15);
            int k = c * 32 + (lane >> 4) * 8 + j;
            dst[i] = f2bf(sgn * W[k * Hout + col]);
        }
    }
}

// ---------------- CSR build, bucket-first (R12): no global degree atomics ----------------
// 1) k_bhist: per-block LDS bucket histogram -> aggregated global adds (~100k, not 1.6M)
__global__ void k_bhist(const int* __restrict__ erow, int e, int nbuck, int* __restrict__ bcnt) {
    __shared__ int hist[MAXBUCK];
    for (int t = threadIdx.x; t < nbuck; t += blockDim.x) hist[t] = 0;
    __syncthreads();
    int chunk = (e + gridDim.x - 1) / gridDim.x;
    int lo = blockIdx.x * chunk, hi = min(e, lo + chunk);
    for (int i = lo + threadIdx.x; i < hi; i += blockDim.x)
        atomicAdd(&hist[erow[i] >> BSHIFT], 1);
    __syncthreads();
    for (int t = threadIdx.x; t < nbuck; t += blockDim.x)
        if (hist[t]) atomicAdd(&bcnt[t], hist[t]);
}

// 2) single-block scan of bucket counts -> boff[0..nbuck] and gcursor init
__global__ void k_bscan(const int* __restrict__ bcnt, int nbuck, int* __restrict__ boff,
                        int* __restrict__ gcursor) {
    __shared__ int lds[MAXBUCK];
    int t = threadIdx.x;
    int v = (t < nbuck) ? bcnt[t] : 0;
    lds[t] = v; __syncthreads();
    for (int off = 1; off < MAXBUCK; off <<= 1) {
        int x = (t >= off) ? lds[t - off] : 0;
        __syncthreads();
        lds[t] += x;
        __syncthreads();
    }
    if (t < nbuck) {
        int ex = lds[t] - v;
        boff[t] = ex;
        gcursor[t] = ex;
        if (t == nbuck - 1) boff[nbuck] = lds[t];
    }
}

// 3) bucketed edge scatter; bedge packed u32 = (col<<8) | (row & 255)
__global__ void k_bscatter(const int* __restrict__ erow, const int* __restrict__ ecol, int e,
                           int nbuck, int* __restrict__ gcursor, u32* __restrict__ bedge) {
    __shared__ int hist[MAXBUCK];
    __shared__ int base[MAXBUCK];
    for (int t = threadIdx.x; t < nbuck; t += blockDim.x) hist[t] = 0;
    __syncthreads();
    int chunk = (e + gridDim.x - 1) / gridDim.x;
    int lo = blockIdx.x * chunk, hi = min(e, lo + chunk);
    for (int i = lo + threadIdx.x; i < hi; i += blockDim.x)
        atomicAdd(&hist[erow[i] >> BSHIFT], 1);
    __syncthreads();
    for (int t = threadIdx.x; t < nbuck; t += blockDim.x) {
        int c = hist[t];
        base[t] = c ? atomicAdd(&gcursor[t], c) : 0;
        hist[t] = 0;
    }
    __syncthreads();
    for (int i = lo + threadIdx.x; i < hi; i += blockDim.x) {
        int r = erow[i];
        int bk = r >> BSHIFT;
        int pos = base[bk] + atomicAdd(&hist[bk], 1);
        bedge[pos] = ((u32)ecol[i] << 8) | (u32)(r & 255);
    }
}

// 4) per-bucket: LDS degree count + LDS scan -> row_ptr/inv_deg, then cols scatter.
__global__ void k_bfill2(const u32* __restrict__ bedge, const int* __restrict__ boff, int n,
                         int* __restrict__ row_ptr, float* __restrict__ inv_deg,
                         int* __restrict__ cols) {
    __shared__ int cnt[256];
    __shared__ int incl[256];
    __shared__ int pos[256];
    int b = blockIdx.x, t = threadIdx.x;
    cnt[t] = 0;
    __syncthreads();
    int rbase = b << BSHIFT;
    int lo = boff[b], hi = boff[b + 1];
    for (int i = lo + t; i < hi; i += 256)
        atomicAdd(&cnt[bedge[i] & 255u], 1);
    __syncthreads();
    int v = cnt[t];
    incl[t] = v;
    __syncthreads();
    for (int off = 1; off < 256; off <<= 1) {
        int x = (t >= off) ? incl[t - off] : 0;
        __syncthreads();
        incl[t] += x;
        __syncthreads();
    }
    int excl = incl[t] - v;
    pos[t] = excl;
    int row = rbase + t;
    if (row < n) {
        row_ptr[row] = lo + excl;
        inv_deg[row] = v > 0 ? 1.f / (float)v : 0.f;
    }
    if (b == (int)gridDim.x - 1 && t == 0) row_ptr[n] = hi;
    __syncthreads();
    for (int i = lo + t; i < hi; i += 256) {
        u32 vv = bedge[i];
        int rl = (int)(vv & 255u);
        int p = lo + atomicAdd(&pos[rl], 1);
        cols[p] = (int)(vv >> 8);
    }
}

// ---------------- SpMM: bf16 X row-major in; A-fragment-packed S (=adj@X scaled) and X out ----------------
// R10: 2 rows per wave (32-lane halves), u64 gathers. R11: XCD swizzle matched with gemm.
__global__ void k_spmm(const u32* __restrict__ X2, const int* __restrict__ row_ptr,
                       const int* __restrict__ cols, const float* __restrict__ inv_deg,
                       u32* __restrict__ Sp, u32* __restrict__ Xp, int n) {
    int blk = xcd_swz(blockIdx.x, gridDim.x);
    int wave = blk * 4 + (int)(threadIdx.x >> 6);
    int lane = threadIdx.x & 63;
    int sl = lane & 31;                 // lane within half
    int row = wave * 2 + (lane >> 5);   // half 0 -> even row, half 1 -> odd row
    if (row >= n) return;
    const u64* X4 = (const u64*)X2;     // lane sl covers u32 cols {2sl, 2sl+1} = 4 bf16
    int beg = row_ptr[row], end = row_ptr[row + 1];
    u64 px = X4[(size_t)row * 32 + sl]; // self row, issued early to overlap gather loop
    float a0 = 0.f, a1 = 0.f, a2 = 0.f, a3 = 0.f;
    for (int j0 = beg; j0 < end; j0 += 32) {
        int cnt = end - j0; if (cnt > 32) cnt = 32;
        int myc = (sl < cnt) ? cols[j0 + sl] : 0;
        int j = 0;
        for (; j + 8 <= cnt; j += 8) {
            int c0 = __shfl(myc, j + 0, 32);
            int c1 = __shfl(myc, j + 1, 32);
            int c2 = __shfl(myc, j + 2, 32);
            int c3 = __shfl(myc, j + 3, 32);
            int c4 = __shfl(myc, j + 4, 32);
            int c5 = __shfl(myc, j + 5, 32);
            int c6 = __shfl(myc, j + 6, 32);
            int c7 = __shfl(myc, j + 7, 32);
            u64 p0 = X4[(size_t)c0 * 32 + sl];
            u64 p1 = X4[(size_t)c1 * 32 + sl];
            u64 p2 = X4[(size_t)c2 * 32 + sl];
            u64 p3 = X4[(size_t)c3 * 32 + sl];
            u64 p4 = X4[(size_t)c4 * 32 + sl];
            u64 p5 = X4[(size_t)c5 * 32 + sl];
            u64 p6 = X4[(size_t)c6 * 32 + sl];
            u64 p7 = X4[(size_t)c7 * 32 + sl];
            u32 l0 = (u32)p0, h0 = (u32)(p0 >> 32);
            u32 l1 = (u32)p1, h1 = (u32)(p1 >> 32);
            u32 l2 = (u32)p2, h2 = (u32)(p2 >> 32);
            u32 l3 = (u32)p3, h3 = (u32)(p3 >> 32);
            u32 l4 = (u32)p4, h4 = (u32)(p4 >> 32);
            u32 l5 = (u32)p5, h5 = (u32)(p5 >> 32);
            u32 l6 = (u32)p6, h6 = (u32)(p6 >> 32);
            u32 l7 = (u32)p7, h7 = (u32)(p7 >> 32);
            a0 += bf2f(l0 & 0xffffu) + bf2f(l1 & 0xffffu) + bf2f(l2 & 0xffffu) + bf2f(l3 & 0xffffu)
                + bf2f(l4 & 0xffffu) + bf2f(l5 & 0xffffu) + bf2f(l6 & 0xffffu) + bf2f(l7 & 0xffffu);
            a1 += bf2f(l0 >> 16) + bf2f(l1 >> 16) + bf2f(l2 >> 16) + bf2f(l3 >> 16)
                + bf2f(l4 >> 16) + bf2f(l5 >> 16) + bf2f(l6 >> 16) + bf2f(l7 >> 16);
            a2 += bf2f(h0 & 0xffffu) + bf2f(h1 & 0xffffu) + bf2f(h2 & 0xffffu) + bf2f(h3 & 0xffffu)
                + bf2f(h4 & 0xffffu) + bf2f(h5 & 0xffffu) + bf2f(h6 & 0xffffu) + bf2f(h7 & 0xffffu);
            a3 += bf2f(h0 >> 16) + bf2f(h1 >> 16) + bf2f(h2 >> 16) + bf2f(h3 >> 16)
                + bf2f(h4 >> 16) + bf2f(h5 >> 16) + bf2f(h6 >> 16) + bf2f(h7 >> 16);
        }
        for (; j + 4 <= cnt; j += 4) {
            int c0 = __shfl(myc, j + 0, 32);
            int c1 = __shfl(myc, j + 1, 32);
            int c2 = __shfl(myc, j + 2, 32);
            int c3 = __shfl(myc, j + 3, 32);
            u64 p0 = X4[(size_t)c0 * 32 + sl];
            u64 p1 = X4[(size_t)c1 * 32 + sl];
            u64 p2 = X4[(size_t)c2 * 32 + sl];
            u64 p3 = X4[(size_t)c3 * 32 + sl];
            u32 l0 = (u32)p0, h0 = (u32)(p0 >> 32);
            u32 l1 = (u32)p1, h1 = (u32)(p1 >> 32);
            u32 l2 = (u32)p2, h2 = (u32)(p2 >> 32);
            u32 l3 = (u32)p3, h3 = (u32)(p3 >> 32);
            a0 += bf2f(l0 & 0xffffu) + bf2f(l1 & 0xffffu) + bf2f(l2 & 0xffffu) + bf2f(l3 & 0xffffu);
            a1 += bf2f(l0 >> 16) + bf2f(l1 >> 16) + bf2f(l2 >> 16) + bf2f(l3 >> 16);
            a2 += bf2f(h0 & 0xffffu) + bf2f(h1 & 0xffffu) + bf2f(h2 & 0xffffu) + bf2f(h3 & 0xffffu);
            a3 += bf2f(h0 >> 16) + bf2f(h1 >> 16) + bf2f(h2 >> 16) + bf2f(h3 >> 16);
        }
        for (; j < cnt; ++j) {
            int c = __shfl(myc, j, 32);
            u64 p = X4[(size_t)c * 32 + sl];
            u32 lo = (u32)p, hi = (u32)(p >> 32);
            a0 += bf2f(lo & 0xffffu);
            a1 += bf2f(lo >> 16);
            a2 += bf2f(hi & 0xffffu);
            a3 += bf2f(hi >> 16);
        }
    }
    float s = inv_deg[row];
    a0 *= s; a1 *= s; a2 *= s; a3 *= s;
    // fragment store: u32 col u0 = 2*sl (even), u1 = u0+1 are adjacent (same cc,qq; jj,jj+1)
    int u0 = sl * 2;
    int cc = u0 >> 4, qq = (u0 >> 2) & 3, jj = u0 & 3;   // jj in {0,2}
    size_t dst = (size_t)(row >> 4) * 1024 + cc * 256 + qq * 64 + (row & 15) * 4 + jj;
    u64 sv = (u64)((u32)f2bf(a0) | ((u32)f2bf(a1) << 16))
           | ((u64)((u32)f2bf(a2) | ((u32)f2bf(a3) << 16)) << 32);
    *(u64*)(Sp + dst) = sv;   // 8B aligned: dst = 4k + {0,2}
    *(u64*)(Xp + dst) = px;
}

// ---------------- fused GEMM + attention combine; A = {S, X}; W = [Wl, -Wh, Wh, Wm] ----------------
// out_low = S@Wl, out_high = S@(-Wh) + X@Wh, out_mlp = X@Wm.
// R13: A-tiles staged ONCE per block into LDS via global_load_lds (was: all 8 waves issuing
// identical 32KB of VGPR-limited global loads -> ~30k-cycle latency-bound wave lifetimes).
// Sp/Xp fragment packing is linear in exactly DMA order (wave-uniform base + lane*16B).
template<int HOUT, bool L1>
__global__ __launch_bounds__(512)
void k_gemm_comb(const u16* __restrict__ Sp, const u16* __restrict__ Xp,
                 const u16* __restrict__ Wp,
                 const float* __restrict__ vl, const float* __restrict__ vh, const float* __restrict__ vm,
                 const float* __restrict__ att, int n,
                 u16* __restrict__ feaOut, float* __restrict__ fOut) {
    constexpr int WN = HOUT / 16;     // col-tile waves: 8 (L1) or 4 (L2)
    constexpr int WM = 8 / WN;        // row-half waves: 1 or 2
    constexpr int MT = 4 / WM;        // 16-row tiles per wave: 4 or 2
    constexpr int ROWS = 64;
    __shared__ __align__(16) u16 As[8192];   // 16KB: 4 rt x 4 c x 512 u16 (linear, = global layout)
    __shared__ __align__(16) u16 Ax[8192];
    int w = threadIdx.x >> 6, lane = threadIdx.x & 63;
    int wn = w % WN, wm = w / WN;
    int ln15 = lane & 15, lq = lane >> 4;
    int tile = xcd_swz(blockIdx.x, gridDim.x);
    int m0 = tile * ROWS;

    // ---- stage A: 32 chunks of 1KB; wave w DMAs chunks {w, w+8} of Sp and of Xp ----
    {
        const u16* gs = Sp + (size_t)tile * 8192;
        const u16* gx = Xp + (size_t)tile * 8192;
        gload_lds16(gs + (size_t)(w    ) * 512 + lane * 8, As + (w    ) * 512);
        gload_lds16(gs + (size_t)(w + 8) * 512 + lane * 8, As + (w + 8) * 512);
        gload_lds16(gx + (size_t)(w    ) * 512 + lane * 8, Ax + (w    ) * 512);
        gload_lds16(gx + (size_t)(w + 8) * 512 + lane * 8, Ax + (w + 8) * 512);
    }

    f32x4 acc[MT][3];
#pragma unroll
    for (int mt = 0; mt < MT; ++mt)
#pragma unroll
        for (int g = 0; g < 3; ++g) { f32x4 z = {0.f, 0.f, 0.f, 0.f}; acc[mt][g] = z; }

    __syncthreads();   // drains the DMA (vmcnt) + all waves see staged A

#pragma unroll
    for (int c = 0; c < 4; ++c) {
        size_t fo = (size_t)(wn * 4 + c) * 512 + lane * 8;
        short8 bl  = *(const short8*)(Wp + (size_t)0 * (HOUT * 128) + fo);
        short8 bhn = *(const short8*)(Wp + (size_t)1 * (HOUT * 128) + fo);
        short8 bhp = *(const short8*)(Wp + (size_t)2 * (HOUT * 128) + fo);
        short8 bm  = *(const short8*)(Wp + (size_t)3 * (HOUT * 128) + fo);
#pragma unroll
        for (int mt = 0; mt < MT; ++mt) {
            int rt = wm * MT + mt;
            int lo = (rt * 4 + c) * 512 + lane * 8;
            short8 as = *(const short8*)(As + lo);
            short8 ax = *(const short8*)(Ax + lo);
            acc[mt][0] = __builtin_amdgcn_mfma_f32_16x16x32_bf16(as, bl,  acc[mt][0], 0, 0, 0);
            acc[mt][1] = __builtin_amdgcn_mfma_f32_16x16x32_bf16(as, bhn, acc[mt][1], 0, 0, 0);
            acc[mt][1] = __builtin_amdgcn_mfma_f32_16x16x32_bf16(ax, bhp, acc[mt][1], 0, 0, 0);
            acc[mt][2] = __builtin_amdgcn_mfma_f32_16x16x32_bf16(ax, bm,  acc[mt][2], 0, 0, 0);
        }
    }

    int vcol = wn * 16 + ln15;
    float vv0 = vl[vcol], vv1 = vh[vcol], vv2 = vm[vcol];

    __shared__ float part[WN][3][ROWS];
    __shared__ float wgt[ROWS][3];
#pragma unroll
    for (int mt = 0; mt < MT; ++mt) {
        float pdg[3][4];
#pragma unroll
        for (int g = 0; g < 3; ++g)
#pragma unroll
            for (int r = 0; r < 4; ++r) pdg[g][r] = 0.f;
#pragma unroll
        for (int r = 0; r < 4; ++r) {
            pdg[0][r] += fmaxf(acc[mt][0][r], 0.f) * vv0;
            pdg[1][r] += fmaxf(acc[mt][1][r], 0.f) * vv1;
            pdg[2][r] += fmaxf(acc[mt][2][r], 0.f) * vv2;
        }
#pragma unroll
        for (int off = 1; off < 16; off <<= 1)
#pragma unroll
            for (int g = 0; g < 3; ++g)
#pragma unroll
                for (int r = 0; r < 4; ++r)
                    pdg[g][r] += __shfl_xor(pdg[g][r], off);
        if (ln15 == 0) {
            int rbase = (wm * MT + mt) * 16 + lq * 4;
#pragma unroll
            for (int g = 0; g < 3; ++g)
#pragma unroll
                for (int r = 0; r < 4; ++r)
                    part[wn][g][rbase + r] = pdg[g][r];
        }
    }
    __syncthreads();
    if (threadIdx.x < ROWS) {
        int row = threadIdx.x;
        float d0 = 0.f, d1 = 0.f, d2 = 0.f;
#pragma unroll
        for (int q = 0; q < WN; ++q) {
            d0 += part[q][0][row];
            d1 += part[q][1][row];
            d2 += part[q][2][row];
        }
        float s0 = 1.f / (1.f + __expf(-d0));
        float s1 = 1.f / (1.f + __expf(-d1));
        float s2 = 1.f / (1.f + __expf(-d2));
        float a0 = (s0 * att[0] + s1 * att[3] + s2 * att[6]) * (1.f / 3.f);
        float a1 = (s0 * att[1] + s1 * att[4] + s2 * att[7]) * (1.f / 3.f);
        float a2 = (s0 * att[2] + s1 * att[5] + s2 * att[8]) * (1.f / 3.f);
        float mx = fmaxf(a0, fmaxf(a1, a2));
        float e0 = __expf(a0 - mx), e1 = __expf(a1 - mx), e2 = __expf(a2 - mx);
        float inv = 3.f / (e0 + e1 + e2);
        wgt[row][0] = e0 * inv;
        wgt[row][1] = e1 * inv;
        wgt[row][2] = e2 * inv;
    }
    __syncthreads();

#pragma unroll
    for (int mt = 0; mt < MT; ++mt)
#pragma unroll
        for (int r = 0; r < 4; ++r) {
            int row_local = (wm * MT + mt) * 16 + lq * 4 + r;
            int row = m0 + row_local;
            if (row < n) {
                int col = wn * 16 + ln15;
                float w0 = wgt[row_local][0], w1 = wgt[row_local][1], w2 = wgt[row_local][2];
                float ol = fmaxf(acc[mt][0][r], 0.f);
                float oh = fmaxf(acc[mt][1][r], 0.f);
                float om = fmaxf(acc[mt][2][r], 0.f);
                float val = w0 * ol + w1 * oh + w2 * om;
                if (L1)
                    feaOut[(size_t)row * HOUT + col] = f2bf(fmaxf(val, 0.f));
                else
                    fOut[(size_t)row * HOUT + col] = val;
            }
        }
}

extern "C" void kernel_launch(void* const* d_in, const int* in_sizes, int n_in,
                              void* d_out, int out_size, void* d_ws, size_t ws_size,
                              hipStream_t stream) {
    const int F = 128;
    int n = in_sizes[0] / F;
    int e = in_sizes[1] / 2;
    int n64 = (n + 63) & ~63;
    int nbuck = (n + (1 << BSHIFT) - 1) >> BSHIFT;
    const float* x = (const float*)d_in[0];
    const int* ei = (const int*)d_in[1];
    const int* erow = ei;
    const int* ecol = ei + e;
    const float *Wl1 = (const float*)d_in[2], *Wh1 = (const float*)d_in[3], *Wm1 = (const float*)d_in[4];
    const float *vl1 = (const float*)d_in[5], *vh1 = (const float*)d_in[6], *vm1 = (const float*)d_in[7];
    const float* att1 = (const float*)d_in[8];
    const float *Wl2 = (const float*)d_in[9], *Wh2 = (const float*)d_in[10], *Wm2 = (const float*)d_in[11];
    const float *vl2 = (const float*)d_in[12], *vh2 = (const float*)d_in[13], *vm2 = (const float*)d_in[14];
    const float* att2 = (const float*)d_in[15];
    float* out = (float*)d_out;

    char* ws = (char*)d_ws;
    size_t off = 0;
    auto alloc = [&](size_t b) -> void* {
        void* p = ws + off;
        off = (off + b + 255) & ~(size_t)255;
        return p;
    };
    int* row_ptr = (int*)alloc((size_t)(n + 1) * 4);
    float* inv_deg = (float*)alloc((size_t)n * 4);
    int* bcnt = (int*)alloc(MAXBUCK * 4);
    int* boff = (int*)alloc((MAXBUCK + 1) * 4);
    int* gcursor = (int*)alloc(MAXBUCK * 4);
    u32* bedge = (u32*)alloc((size_t)e * 4);
    int* cols = (int*)alloc((size_t)e * 4);
    u32* Sp = (u32*)alloc((size_t)n64 * 64 * 4);
    u32* Xp = (u32*)alloc((size_t)n64 * 64 * 4);
    u32* Fp = (u32*)alloc((size_t)n64 * 64 * 4);
    u16* Xb = (u16*)alloc((size_t)n * 128 * 2);
    u16* fea = (u16*)alloc((size_t)n * 128 * 2);
    u16* Wp1 = (u16*)alloc((size_t)4 * 128 * 128 * 2);
    u16* Wp2 = (u16*)alloc((size_t)4 * 64 * 128 * 2);
    (void)ws_size; (void)n_in; (void)out_size;

    k_prep<<<CASTBLK + 16, 256, 0, stream>>>((const float4*)x, (u32*)Xb, (long)n * 32,
                                             Wl1, Wh1, Wm1, Wl2, Wh2, Wm2, Wp1, Wp2);

    hipMemsetAsync(bcnt, 0, (size_t)MAXBUCK * 4, stream);
    k_bhist<<<256, 256, 0, stream>>>(erow, e, nbuck, bcnt);
    k_bscan<<<1, MAXBUCK, 0, stream>>>(bcnt, nbuck, boff, gcursor);
    k_bscatter<<<256, 256, 0, stream>>>(erow, ecol, e, nbuck, gcursor, bedge);
    k_bfill2<<<nbuck, 256, 0, stream>>>(bedge, boff, n, row_ptr, inv_deg, cols);

    int wb = (n + 7) / 8;      // 4 waves/block x 2 rows/wave = 8 rows/block
    int gb = n64 / 64;

    // layer 1
    k_spmm<<<wb, 256, 0, stream>>>((const u32*)Xb, row_ptr, cols, inv_deg, Sp, Xp, n);
    k_gemm_comb<128, true><<<gb, 512, 0, stream>>>((const u16*)Sp, (const u16*)Xp,
                                                   Wp1, vl1, vh1, vm1, att1, n, fea, nullptr);

    // layer 2
    k_spmm<<<wb, 256, 0, stream>>>((const u32*)fea, row_ptr, cols, inv_deg, Sp, Fp, n);
    k_gemm_comb<64, false><<<gb, 512, 0, stream>>>((const u16*)Sp, (const u16*)Fp,
                                                   Wp2, vl2, vh2, vm2, att2, n, nullptr, out);
}